// Round 9
// baseline (1191.141 us; speedup 1.0000x reference)
//
#include <hip/hip_runtime.h>

// ---------------------------------------------------------------------------
// Hetero GraphSAGE (2 layers) + edge decoder.
// R1: CSR-gather aggregation. R4: algebraic restructure (U/V decoder split,
//     weight folding, project-before-aggregate). FLOP 1.23e11 -> 5.3e10.
// R5: bf16 MFMA GEMMs + bf16 activations. R6: fp16 U/V, fused CSR aux.
// R8: two-pass LDS-binned CSR fill (108MB scattered writes -> ~14MB).
// R9: mgemm retile 128x128x(2 col-blocks) -> 64x256 (A+Add fetched ONCE;
//     weights L2-resident) + register double-buffer prefetch (loads for
//     tile k+1 issued before MFMA of tile k). Old: 97us/dispatch,
//     latency-bound (MfmaUtil 5%, VALUBusy 17%, 1.3TB/s).
// ---------------------------------------------------------------------------

constexpr int NS = 100000, NT = 20000;
constexpr int E_EDGES = 800000, EL_EDGES = 200000;
constexpr int DS = 256, DT = 128, H = 256;

constexpr int NB_T = 79, SH_T = 8, VB_T = 17;
constexpr int NB_S = 98, SH_S = 10, VB_S = 15;
constexpr int BIN_CAP = 96, CHUNK = 2048;

typedef __attribute__((ext_vector_type(8))) short short8;
typedef __attribute__((ext_vector_type(4))) float float4v;
typedef __attribute__((ext_vector_type(8))) _Float16 half8v;
typedef unsigned short ushort_t;

__device__ __forceinline__ float bf2f(unsigned int u) {
    union { unsigned int i; float f; } x; x.i = u << 16; return x.f;
}
__device__ __forceinline__ unsigned short f2bf(float f) {
    union { float f; unsigned int i; } x; x.f = f;
    unsigned int r = x.i + 0x7FFFu + ((x.i >> 16) & 1u);   // RNE
    return (unsigned short)(r >> 16);
}

// --------------------------- MFMA GEMM -------------------------------------
// C[M,256] = op( A1@W1^T [+ A2@W2^T] [+ Add] [+ bias] )
// Tile 64(M) x 256(N) x 32(K): one block covers all N -> A read once.
// 4 waves, wave w owns cols [64w, 64w+64): 4x4 16x16x32 MFMA tiles.
// Register double-buffer: next K-tile loads issued before current MFMAs.
// flags: 1 = relu, 2 = fp16 output (else bf16)
__global__ __launch_bounds__(256) void mgemm_kernel(
    const ushort_t* __restrict__ A1, const ushort_t* __restrict__ W1, int K1,
    const ushort_t* __restrict__ A2, const ushort_t* __restrict__ W2, int K2,
    const ushort_t* __restrict__ Add, const float* __restrict__ bias,
    void* __restrict__ Cout, int M, int flags)
{
    __shared__ ushort_t As[64][40];
    __shared__ ushort_t Bs[256][40];
    const int tid = threadIdx.x;
    const int row0 = blockIdx.x * 64;
    const int wave = tid >> 6, lane = tid & 63;
    const int wcol = wave * 64;
    const int m16 = lane & 15, quad = lane >> 4;
    const int sr = tid >> 2;                 // staging row 0..63
    const int skc = (tid & 3) * 8;           // k-chunk (ushorts): 0,8,16,24

    float4v acc[4][4];
#pragma unroll
    for (int i = 0; i < 4; i++)
#pragma unroll
        for (int j = 0; j < 4; j++) acc[i][j] = (float4v){0.f, 0.f, 0.f, 0.f};

#pragma unroll 1
    for (int pass = 0; pass < 2; pass++) {
        const ushort_t* A = pass ? A2 : A1;
        const ushort_t* W = pass ? W2 : W1;
        const int K = pass ? K2 : K1;
        if (!A) break;
        const int gra = row0 + sr;
        const bool oka = gra < M;
        const ushort_t* Ap = A + (size_t)gra * K + skc;
        const ushort_t* Wp = W + (size_t)sr * K + skc;

        uint4 a_r = make_uint4(0, 0, 0, 0);
        uint4 b_r[4];
        if (oka) a_r = *(const uint4*)Ap;
#pragma unroll
        for (int i = 0; i < 4; i++)
            b_r[i] = *(const uint4*)(Wp + (size_t)(64 * i) * K);

        for (int k0 = 0; k0 < K; k0 += 32) {
            __syncthreads();                 // prev compute done reading LDS
            *(uint4*)&As[sr][skc] = a_r;
#pragma unroll
            for (int i = 0; i < 4; i++)
                *(uint4*)&Bs[sr + 64 * i][skc] = b_r[i];
            __syncthreads();                 // LDS ready
            if (k0 + 32 < K) {               // prefetch next tile (hidden by MFMA)
                a_r = make_uint4(0, 0, 0, 0);
                if (oka) a_r = *(const uint4*)(Ap + k0 + 32);
#pragma unroll
                for (int i = 0; i < 4; i++)
                    b_r[i] = *(const uint4*)(Wp + (size_t)(64 * i) * K + k0 + 32);
            }
            short8 af[4], bf[4];
#pragma unroll
            for (int i = 0; i < 4; i++)
                af[i] = *(const short8*)&As[i * 16 + m16][quad * 8];
#pragma unroll
            for (int j = 0; j < 4; j++)
                bf[j] = *(const short8*)&Bs[wcol + j * 16 + m16][quad * 8];
#pragma unroll
            for (int i = 0; i < 4; i++)
#pragma unroll
                for (int j = 0; j < 4; j++)
                    acc[i][j] = __builtin_amdgcn_mfma_f32_16x16x32_bf16(
                        af[i], bf[j], acc[i][j], 0, 0, 0);
        }
    }

    const bool relu = flags & 1, f16out = flags & 2;
#pragma unroll
    for (int i = 0; i < 4; i++) {
        const int rbase = row0 + i * 16 + quad * 4;
#pragma unroll
        for (int r = 0; r < 4; r++) {
            const int row = rbase + r;
            if (row >= M) continue;
#pragma unroll
            for (int j = 0; j < 4; j++) {
                const int col = wcol + j * 16 + m16;
                float v = acc[i][j][r];
                if (Add) v += bf2f((unsigned int)Add[(size_t)row * 256 + col]);
                if (bias) v += bias[col];
                if (relu) v = fmaxf(v, 0.f);
                if (f16out) ((_Float16*)Cout)[(size_t)row * 256 + col] = (_Float16)v;
                else ((ushort_t*)Cout)[(size_t)row * 256 + col] = f2bf(v);
            }
        }
    }
}

// --------------------- batched fp32 -> bf16 convert ------------------------
struct CvtJobs {
    const float* src[14];
    ushort_t* dst[14];
    int n4[14];
    int cnt;
};

__global__ __launch_bounds__(256) void cvt_kernel(CvtJobs jb, int total4)
{
    int t = blockIdx.x * blockDim.x + threadIdx.x;
    if (t >= total4) return;
    int idx = t;
    for (int k = 0; k < jb.cnt; k++) {
        if (idx < jb.n4[k]) {
            float4 v = ((const float4*)jb.src[k])[idx];
            uint2 o;
            o.x = (unsigned int)f2bf(v.x) | ((unsigned int)f2bf(v.y) << 16);
            o.y = (unsigned int)f2bf(v.z) | ((unsigned int)f2bf(v.w) << 16);
            *(uint2*)(jb.dst[k] + (size_t)idx * 4) = o;
            return;
        }
        idx -= jb.n4[k];
    }
}

// -------------- decoder weight folding (one fused kernel) ------------------
__global__ __launch_bounds__(256) void fold_kernel(
    const float* __restrict__ Wd1, const float* __restrict__ bd1,
    const float* __restrict__ Wlin_s, const float* __restrict__ blin_s,
    const float* __restrict__ Wlin_t, const float* __restrict__ blin_t,
    float* __restrict__ Wc_s, float* __restrict__ Wc_t,
    float* __restrict__ bu, float* __restrict__ bv)
{
    const int b = blockIdx.x, t = threadIdx.x;
    if (b < 256) {
        float s = 0.f;
        for (int k = 0; k < 256; k++) s += Wd1[b * 512 + k] * Wlin_s[k * 256 + t];
        Wc_s[b * 256 + t] = s;
    } else if (b < 512) {
        const int h = b - 256;
        float s = 0.f;
        for (int k = 0; k < 256; k++) s += Wd1[h * 512 + 256 + k] * Wlin_t[k * 256 + t];
        Wc_t[h * 256 + t] = s;
    } else {
        float su = 0.f, sv = 0.f;
        for (int k = 0; k < 256; k++) {
            su += Wd1[t * 512 + k] * blin_s[k];
            sv += Wd1[t * 512 + 256 + k] * blin_t[k];
        }
        bu[t] = bd1[t] + su;
        bv[t] = sv;
    }
}

// --------------------------- CSR build -------------------------------------
__global__ void count_kernel(const int* __restrict__ src, const int* __restrict__ dst,
                             int* __restrict__ cnt_s, int* __restrict__ cnt_t, int E)
{
    int e = blockIdx.x * blockDim.x + threadIdx.x;
    if (e < E) {
        atomicAdd(&cnt_s[src[e]], 1);
        atomicAdd(&cnt_t[dst[e]], 1);
    }
}

__global__ __launch_bounds__(256) void psum_kernel(
    const int* __restrict__ cnt_s, const int* __restrict__ cnt_t,
    int* __restrict__ bsum_s, int* __restrict__ bsum_t, int nbS)
{
    const bool isS = (int)blockIdx.x < nbS;
    const int blk = isS ? blockIdx.x : blockIdx.x - nbS;
    const int N = isS ? NS : NT;
    const int* cnt = isS ? cnt_s : cnt_t;
    int* bsum = isS ? bsum_s : bsum_t;
    __shared__ int sdata[256];
    const int t = threadIdx.x;
    const int base = blk * 1024;
    int s = 0;
    for (int i = t; i < 1024; i += 256) {
        int idx = base + i;
        s += (idx < N) ? cnt[idx] : 0;
    }
    sdata[t] = s; __syncthreads();
    for (int off = 128; off > 0; off >>= 1) {
        if (t < off) sdata[t] += sdata[t + off];
        __syncthreads();
    }
    if (t == 0) bsum[blk] = sdata[0];
}

__global__ void sbsum_kernel(int* __restrict__ bsum_s, int* __restrict__ bsum_t,
                             int nbS, int nbT)
{
    if (threadIdx.x != 0) return;
    int* b = blockIdx.x ? bsum_t : bsum_s;
    int nb = blockIdx.x ? nbT : nbS;
    int run = 0;
    for (int i = 0; i < nb; i++) { int v = b[i]; b[i] = run; run += v; }
}

__global__ __launch_bounds__(256) void sblock_kernel(
    const int* __restrict__ cnt_s, const int* __restrict__ cnt_t,
    const int* __restrict__ bsum_s, const int* __restrict__ bsum_t,
    int* __restrict__ rowptr_s, int* __restrict__ rowptr_t, int nbS)
{
    const bool isS = (int)blockIdx.x < nbS;
    const int blk = isS ? blockIdx.x : blockIdx.x - nbS;
    const int N = isS ? NS : NT;
    const int* cnt = isS ? cnt_s : cnt_t;
    const int* bsum = isS ? bsum_s : bsum_t;
    int* rowptr = isS ? rowptr_s : rowptr_t;
    __shared__ int sc[256];
    const int t = threadIdx.x;
    const int base = blk * 1024 + t * 4;
    int v[4]; int s = 0;
#pragma unroll
    for (int j = 0; j < 4; j++) {
        int idx = base + j;
        v[j] = (idx < N) ? cnt[idx] : 0;
        s += v[j];
    }
    sc[t] = s; __syncthreads();
    for (int off = 1; off < 256; off <<= 1) {
        int add = (t >= off) ? sc[t - off] : 0;
        __syncthreads();
        sc[t] += add;
        __syncthreads();
    }
    int excl = sc[t] - s + bsum[blk];
#pragma unroll
    for (int j = 0; j < 4; j++) {
        int idx = base + j;
        if (idx < N) rowptr[idx] = excl;
        if (idx == N - 1) rowptr[N] = excl + v[j];
        excl += v[j];
    }
}

__global__ void binit_kernel(const int* __restrict__ rowptr_t,
                             const int* __restrict__ rowptr_s,
                             int* __restrict__ gcur_t, int* __restrict__ gcur_s)
{
    int t = threadIdx.x;
    if (t < NB_T) gcur_t[t] = rowptr_t[t << SH_T];
    if (t < NB_S) gcur_s[t] = rowptr_s[t << SH_S];
}

__global__ __launch_bounds__(256) void binA_kernel(
    const int* __restrict__ key, const int* __restrict__ val, int E,
    int nbins, int shift, int vbits,
    int* __restrict__ gcur, unsigned* __restrict__ stg)
{
    __shared__ unsigned bins[NB_S * BIN_CAP];
    __shared__ int lcnt[NB_S], gbase[NB_S];
    const int tid = threadIdx.x;
    const int base = blockIdx.x * CHUNK;
    for (int i = tid; i < nbins; i += 256) lcnt[i] = 0;
    __syncthreads();
    const unsigned lowmask = (1u << shift) - 1u;
#pragma unroll
    for (int k = 0; k < CHUNK / 256; k++) {
        int e = base + k * 256 + tid;
        if (e < E) {
            int kk = key[e];
            int b = kk >> shift;
            unsigned pk = (((unsigned)kk & lowmask) << vbits) | (unsigned)val[e];
            int c = atomicAdd(&lcnt[b], 1);
            if (c < BIN_CAP) bins[b * BIN_CAP + c] = pk;
            else { int p = atomicAdd(&gcur[b], 1); stg[p] = pk; }
        }
    }
    __syncthreads();
    if (tid < nbins) gbase[tid] = atomicAdd(&gcur[tid], min(lcnt[tid], BIN_CAP));
    __syncthreads();
    for (int b = 0; b < nbins; b++) {
        int c = min(lcnt[b], BIN_CAP);
        for (int i = tid; i < c; i += 256) stg[gbase[b] + i] = bins[b * BIN_CAP + i];
    }
}

__global__ __launch_bounds__(256) void binB_kernel(
    const unsigned* __restrict__ stg, const int* __restrict__ rowptr,
    int N, int node_per, int vbits, int* __restrict__ colout)
{
    __shared__ int cur[1024];
    const int tid = threadIdx.x;
    const int node0 = blockIdx.x * node_per;
    const int nn = min(node_per, N - node0);
    for (int i = tid; i < nn; i += 256) cur[i] = rowptr[node0 + i];
    const int estart = rowptr[node0];
    const int eend = rowptr[node0 + nn];
    __syncthreads();
    const unsigned vmask = (1u << vbits) - 1u;
    for (int i = estart + tid; i < eend; i += 256) {
        unsigned v = stg[i];
        int kl = (int)(v >> vbits);
        int pos = atomicAdd(&cur[kl], 1);
        colout[pos] = (int)(v & vmask);
    }
}

// ------------------- gather mean (bf16 rows, fp32 accum) -------------------
__global__ __launch_bounds__(256) void gather_mean_kernel(
    const ushort_t* __restrict__ X, const int* __restrict__ rowptr,
    const int* __restrict__ cnt, const int* __restrict__ col,
    ushort_t* __restrict__ out, int N)
{
    const int node = blockIdx.x * 8 + (threadIdx.x >> 5);
    const int c = (threadIdx.x & 31) * 8;
    if (node >= N) return;
    const int beg = rowptr[node];
    const int deg = cnt[node];
    const int end = beg + deg;
    float a[8] = {0, 0, 0, 0, 0, 0, 0, 0};
    float b[8] = {0, 0, 0, 0, 0, 0, 0, 0};
    int i = beg;
    for (; i + 1 < end; i += 2) {
        uint4 v = *(const uint4*)&X[(size_t)col[i] * 256 + c];
        uint4 w = *(const uint4*)&X[(size_t)col[i + 1] * 256 + c];
        a[0] += bf2f(v.x & 0xffff); a[1] += bf2f(v.x >> 16);
        a[2] += bf2f(v.y & 0xffff); a[3] += bf2f(v.y >> 16);
        a[4] += bf2f(v.z & 0xffff); a[5] += bf2f(v.z >> 16);
        a[6] += bf2f(v.w & 0xffff); a[7] += bf2f(v.w >> 16);
        b[0] += bf2f(w.x & 0xffff); b[1] += bf2f(w.x >> 16);
        b[2] += bf2f(w.y & 0xffff); b[3] += bf2f(w.y >> 16);
        b[4] += bf2f(w.z & 0xffff); b[5] += bf2f(w.z >> 16);
        b[6] += bf2f(w.w & 0xffff); b[7] += bf2f(w.w >> 16);
    }
    if (i < end) {
        uint4 v = *(const uint4*)&X[(size_t)col[i] * 256 + c];
        a[0] += bf2f(v.x & 0xffff); a[1] += bf2f(v.x >> 16);
        a[2] += bf2f(v.y & 0xffff); a[3] += bf2f(v.y >> 16);
        a[4] += bf2f(v.z & 0xffff); a[5] += bf2f(v.z >> 16);
        a[6] += bf2f(v.w & 0xffff); a[7] += bf2f(v.w >> 16);
    }
    float inv = 1.f / fmaxf((float)deg, 1.f);
    uint4 o;
    o.x = (unsigned int)f2bf((a[0] + b[0]) * inv) | ((unsigned int)f2bf((a[1] + b[1]) * inv) << 16);
    o.y = (unsigned int)f2bf((a[2] + b[2]) * inv) | ((unsigned int)f2bf((a[3] + b[3]) * inv) << 16);
    o.z = (unsigned int)f2bf((a[4] + b[4]) * inv) | ((unsigned int)f2bf((a[5] + b[5]) * inv) << 16);
    o.w = (unsigned int)f2bf((a[6] + b[6]) * inv) | ((unsigned int)f2bf((a[7] + b[7]) * inv) << 16);
    *(uint4*)&out[(size_t)node * 256 + c] = o;
}

// ------------------------- per-edge score (fp16 U/V) -----------------------
__global__ __launch_bounds__(256) void edge_score_kernel(
    const _Float16* __restrict__ U, const _Float16* __restrict__ V,
    const int* __restrict__ ls, const int* __restrict__ ld,
    const float* __restrict__ Wd2, const float* __restrict__ bd2,
    float* __restrict__ out, int EL)
{
    const int l32 = threadIdx.x & 31;
    const int e = blockIdx.x * 8 + (threadIdx.x >> 5);
    if (e >= EL) return;
    const int c = l32 * 8;
    half8v u = *(const half8v*)&U[(size_t)ls[e] * 256 + c];
    half8v v = *(const half8v*)&V[(size_t)ld[e] * 256 + c];
    float4 w0 = *(const float4*)&Wd2[c];
    float4 w1 = *(const float4*)&Wd2[c + 4];
    float s = fmaxf((float)u[0] + (float)v[0], 0.f) * w0.x
            + fmaxf((float)u[1] + (float)v[1], 0.f) * w0.y
            + fmaxf((float)u[2] + (float)v[2], 0.f) * w0.z
            + fmaxf((float)u[3] + (float)v[3], 0.f) * w0.w
            + fmaxf((float)u[4] + (float)v[4], 0.f) * w1.x
            + fmaxf((float)u[5] + (float)v[5], 0.f) * w1.y
            + fmaxf((float)u[6] + (float)v[6], 0.f) * w1.z
            + fmaxf((float)u[7] + (float)v[7], 0.f) * w1.w;
#pragma unroll
    for (int m = 16; m >= 1; m >>= 1) s += __shfl_xor(s, m, 64);
    if (l32 == 0) out[e] = s + bd2[0];
}

// ---------------------------------------------------------------------------
extern "C" void kernel_launch(void* const* d_in, const int* in_sizes, int n_in,
                              void* d_out, int out_size, void* d_ws, size_t ws_size,
                              hipStream_t stream)
{
    const float* x_sotu  = (const float*)d_in[0];
    const float* x_taxon = (const float*)d_in[1];
    const int* edge_src  = (const int*)d_in[2];
    const int* edge_dst  = (const int*)d_in[3];
    const int* label_src = (const int*)d_in[4];
    const int* label_dst = (const int*)d_in[5];
    const float* Wl1_st = (const float*)d_in[6];
    const float* bl1_st = (const float*)d_in[7];
    const float* Wr1_st = (const float*)d_in[8];
    const float* Wl1_ts = (const float*)d_in[9];
    const float* bl1_ts = (const float*)d_in[10];
    const float* Wr1_ts = (const float*)d_in[11];
    const float* Wl2_st = (const float*)d_in[12];
    const float* bl2_st = (const float*)d_in[13];
    const float* Wr2_st = (const float*)d_in[14];
    const float* Wl2_ts = (const float*)d_in[15];
    const float* bl2_ts = (const float*)d_in[16];
    const float* Wr2_ts = (const float*)d_in[17];
    const float* Wlin_s = (const float*)d_in[18];
    const float* blin_s = (const float*)d_in[19];
    const float* Wlin_t = (const float*)d_in[20];
    const float* blin_t = (const float*)d_in[21];
    const float* Wd1 = (const float*)d_in[22];
    const float* bd1 = (const float*)d_in[23];
    const float* Wd2 = (const float*)d_in[24];
    const float* bd2 = (const float*)d_in[25];

    // -------- workspace layout --------
    int* wi = (int*)d_ws;
    size_t io = 0;
    int* cnt_s   = wi + io; io += NS;
    int* cnt_t   = wi + io; io += NT;
    int* rowptr_s = wi + io; io += NS + 8;
    int* rowptr_t = wi + io; io += NT + 8;
    int* col_s   = wi + io; io += E_EDGES;
    int* col_t   = wi + io; io += E_EDGES;
    unsigned* stg_s = (unsigned*)(wi + io); io += E_EDGES;
    unsigned* stg_t = (unsigned*)(wi + io); io += E_EDGES;
    int* bsum_s  = wi + io; io += 128;
    int* bsum_t  = wi + io; io += 128;
    int* gcur_t  = wi + io; io += 128;
    int* gcur_s  = wi + io; io += 128;
    io = (io + 63) & ~(size_t)63;

    ushort_t* wb = (ushort_t*)(wi + io);
    size_t bo = 0;
    ushort_t* m_s  = wb + bo; bo += (size_t)NS * H;   // U (fp16) overlays m_s
    ushort_t* h1_s = wb + bo; bo += (size_t)NS * H;
    ushort_t* m_t  = wb + bo; bo += (size_t)NT * H;   // V (fp16) overlays m_t
    ushort_t* h1_t = wb + bo; bo += (size_t)NT * H;
    ushort_t* h2_s = wb + bo; bo += (size_t)NS * H;
    ushort_t* h2_t = wb + bo; bo += (size_t)NT * H;
    ushort_t* xs_b = wb + bo; bo += (size_t)NS * DS;
    ushort_t* xt_b = wb + bo; bo += (size_t)NT * DT;
    ushort_t* Pt   = wb + bo; bo += (size_t)NT * H;
    ushort_t* wb_l1st = wb + bo; bo += H * DS;
    ushort_t* wb_r1st = wb + bo; bo += H * DT;
    ushort_t* wb_l1ts = wb + bo; bo += H * DT;
    ushort_t* wb_r1ts = wb + bo; bo += H * DS;
    ushort_t* wb_l2st = wb + bo; bo += H * H;
    ushort_t* wb_r2st = wb + bo; bo += H * H;
    ushort_t* wb_l2ts = wb + bo; bo += H * H;
    ushort_t* wb_r2ts = wb + bo; bo += H * H;
    ushort_t* wcb_s   = wb + bo; bo += H * H;
    ushort_t* wcb_t   = wb + bo; bo += H * H;
    bo = (bo + 7) & ~(size_t)7;

    float* wf = (float*)(wb + bo);
    size_t fo = 0;
    float* Wc_s = wf + fo; fo += H * H;
    float* Wc_t = wf + fo; fo += H * H;
    float* bu   = wf + fo; fo += 256;
    float* bv   = wf + fo; fo += 256;

    _Float16* U = (_Float16*)m_s;
    _Float16* V = (_Float16*)m_t;

    const dim3 blk(256);
    auto mg = [](int M) { return dim3((M + 63) / 64); };
    const int nbS = (NS + 1023) / 1024;   // 98
    const int nbT = (NT + 1023) / 1024;   // 20
    const int nA = (E_EDGES + CHUNK - 1) / CHUNK;

    // ---- decoder weight folding ----
    fold_kernel<<<513, blk, 0, stream>>>(Wd1, bd1, Wlin_s, blin_s, Wlin_t, blin_t,
                                         Wc_s, Wc_t, bu, bv);

    // ---- batched fp32->bf16 conversion ----
    {
        CvtJobs jb; int c = 0, total4 = 0;
        auto addj = [&](const float* s, ushort_t* d, int n) {
            jb.src[c] = s; jb.dst[c] = d; jb.n4[c] = n / 4; total4 += n / 4; c++;
        };
        addj(x_sotu, xs_b, NS * DS);
        addj(x_taxon, xt_b, NT * DT);
        addj(Wl1_st, wb_l1st, H * DS);
        addj(Wr1_st, wb_r1st, H * DT);
        addj(Wl1_ts, wb_l1ts, H * DT);
        addj(Wr1_ts, wb_r1ts, H * DS);
        addj(Wl2_st, wb_l2st, H * H);
        addj(Wr2_st, wb_r2st, H * H);
        addj(Wl2_ts, wb_l2ts, H * H);
        addj(Wr2_ts, wb_r2ts, H * H);
        addj(Wc_s, wcb_s, H * H);
        addj(Wc_t, wcb_t, H * H);
        jb.cnt = c;
        cvt_kernel<<<(total4 + 255) / 256, blk, 0, stream>>>(jb, total4);
    }

    // ---- CSR build: count -> scan -> binned two-pass fill ----
    hipMemsetAsync(cnt_s, 0, (size_t)(NS + NT) * sizeof(int), stream);
    count_kernel<<<(E_EDGES + 255) / 256, blk, 0, stream>>>(edge_src, edge_dst,
                                                            cnt_s, cnt_t, E_EDGES);
    psum_kernel<<<nbS + nbT, blk, 0, stream>>>(cnt_s, cnt_t, bsum_s, bsum_t, nbS);
    sbsum_kernel<<<2, 64, 0, stream>>>(bsum_s, bsum_t, nbS, nbT);
    sblock_kernel<<<nbS + nbT, blk, 0, stream>>>(cnt_s, cnt_t, bsum_s, bsum_t,
                                                 rowptr_s, rowptr_t, nbS);
    binit_kernel<<<1, blk, 0, stream>>>(rowptr_t, rowptr_s, gcur_t, gcur_s);
    binA_kernel<<<nA, blk, 0, stream>>>(edge_dst, edge_src, E_EDGES,
                                        NB_T, SH_T, VB_T, gcur_t, stg_t);
    binA_kernel<<<nA, blk, 0, stream>>>(edge_src, edge_dst, E_EDGES,
                                        NB_S, SH_S, VB_S, gcur_s, stg_s);
    binB_kernel<<<NB_T, blk, 0, stream>>>(stg_t, rowptr_t, NT, 1 << SH_T, VB_T, col_t);
    binB_kernel<<<NB_S, blk, 0, stream>>>(stg_s, rowptr_s, NS, 1 << SH_S, VB_S, col_s);

    // ---- layer 1 ----
    mgemm_kernel<<<mg(NT), blk, 0, stream>>>(xt_b, wb_l1ts, DT, nullptr, nullptr, 0,
                                             nullptr, nullptr, Pt, NT, 0);
    gather_mean_kernel<<<(NT + 7) / 8, blk, 0, stream>>>(
        xs_b, rowptr_t, cnt_t, col_t, m_t, NT);
    gather_mean_kernel<<<(NS + 7) / 8, blk, 0, stream>>>(
        Pt, rowptr_s, cnt_s, col_s, m_s, NS);
    mgemm_kernel<<<mg(NT), blk, 0, stream>>>(m_t, wb_l1st, H, xt_b, wb_r1st, DT,
                                             nullptr, bl1_st, h1_t, NT, 1);
    mgemm_kernel<<<mg(NS), blk, 0, stream>>>(xs_b, wb_r1ts, DS, nullptr, nullptr, 0,
                                             m_s, bl1_ts, h1_s, NS, 1);

    // ---- layer 2 ----
    mgemm_kernel<<<mg(NT), blk, 0, stream>>>(h1_t, wb_l2ts, H, nullptr, nullptr, 0,
                                             nullptr, nullptr, Pt, NT, 0);
    gather_mean_kernel<<<(NT + 7) / 8, blk, 0, stream>>>(
        h1_s, rowptr_t, cnt_t, col_t, m_t, NT);
    gather_mean_kernel<<<(NS + 7) / 8, blk, 0, stream>>>(
        Pt, rowptr_s, cnt_s, col_s, m_s, NS);
    mgemm_kernel<<<mg(NT), blk, 0, stream>>>(m_t, wb_l2st, H, h1_t, wb_r2st, H,
                                             nullptr, bl2_st, h2_t, NT, 1);
    mgemm_kernel<<<mg(NS), blk, 0, stream>>>(h1_s, wb_r2ts, H, nullptr, nullptr, 0,
                                             m_s, bl2_ts, h2_s, NS, 1);

    // ---- decoder: U/V node potentials (fp16 out) + per-edge reduce ----
    mgemm_kernel<<<mg(NS), blk, 0, stream>>>(h2_s, wcb_s, H, nullptr, nullptr, 0,
                                             nullptr, bu, U, NS, 2);
    mgemm_kernel<<<mg(NT), blk, 0, stream>>>(h2_t, wcb_t, H, nullptr, nullptr, 0,
                                             nullptr, bv, V, NT, 2);
    edge_score_kernel<<<(EL_EDGES + 7) / 8, blk, 0, stream>>>(
        U, V, label_src, label_dst, Wd2, bd2, (float*)d_out, EL_EDGES);
}

// Round 10
// 985.067 us; speedup vs baseline: 1.2092x; 1.2092x over previous
//
#include <hip/hip_runtime.h>

// ---------------------------------------------------------------------------
// Hetero GraphSAGE (2 layers) + edge decoder.
// R1: CSR-gather aggregation. R4: algebraic restructure (U/V decoder split,
//     weight folding, project-before-aggregate). FLOP 1.23e11 -> 5.3e10.
// R5: bf16 MFMA GEMMs + bf16 activations. R6: fp16 U/V, fused CSR aux.
// R8: two-pass LDS-binned CSR fill (108MB scattered writes -> ~14MB). 994us.
// R9 FAILED: 64x256 tile + reg prefetch -> WRITE_SIZE doubled (50->104MB),
//     MfmaUtil 5->3.6%, 97->141us/dispatch. REVERTED to R8 128x128 loop.
// R10: XCD-paired block swizzle: the two col-blocks sharing an A row-group
//     are 8 dispatch indices apart -> same XCD L2 -> A+Add fetched from HBM
//     once. (mgemm regs 72V+64A=136/wave caps occupancy ~3 waves/SIMD; if
//     swizzle under-delivers, next lever is a smaller per-wave acc tile.)
// ---------------------------------------------------------------------------

constexpr int NS = 100000, NT = 20000;
constexpr int E_EDGES = 800000, EL_EDGES = 200000;
constexpr int DS = 256, DT = 128, H = 256;

constexpr int NB_T = 79, SH_T = 8, VB_T = 17;
constexpr int NB_S = 98, SH_S = 10, VB_S = 15;
constexpr int BIN_CAP = 96, CHUNK = 2048;

typedef __attribute__((ext_vector_type(8))) short short8;
typedef __attribute__((ext_vector_type(4))) float float4v;
typedef __attribute__((ext_vector_type(8))) _Float16 half8v;
typedef unsigned short ushort_t;

__device__ __forceinline__ float bf2f(unsigned int u) {
    union { unsigned int i; float f; } x; x.i = u << 16; return x.f;
}
__device__ __forceinline__ unsigned short f2bf(float f) {
    union { float f; unsigned int i; } x; x.f = f;
    unsigned int r = x.i + 0x7FFFu + ((x.i >> 16) & 1u);   // RNE
    return (unsigned short)(r >> 16);
}

// --------------------------- MFMA GEMM -------------------------------------
// C[M,256] = op( A1@W1^T [+ A2@W2^T] [+ Add] [+ bias] )
// R8-proven inner loop: 128x128 tile, BK=32, LDS stride 40.
// 1D grid, XCD-paired swizzle: col-block pair for one row-group sits 8
// dispatch indices apart (same XCD under round-robin) for A/Add L2 reuse.
// flags: 1 = relu, 2 = fp16 output (else bf16)
__global__ __launch_bounds__(256) void mgemm_kernel(
    const ushort_t* __restrict__ A1, const ushort_t* __restrict__ W1, int K1,
    const ushort_t* __restrict__ A2, const ushort_t* __restrict__ W2, int K2,
    const ushort_t* __restrict__ Add, const float* __restrict__ bias,
    void* __restrict__ Cout, int M, int flags)
{
    __shared__ ushort_t As[128][40];
    __shared__ ushort_t Bs[128][40];
    const int tid = threadIdx.x;

    // ---- XCD-paired swizzle: bid -> (rowblk, colblk) ----
    const int nx = (M + 127) >> 7;          // row-blocks
    const int nx8 = nx & ~7;                // swizzled region (multiple of 8)
    const int bid = blockIdx.x;
    int rowblk, colblk;
    if (bid < nx8 * 2) {
        const int group = bid >> 4;         // 16 blocks per group
        const int xcd = bid & 7;
        const int half = (bid >> 3) & 1;
        rowblk = group * 8 + xcd;
        colblk = half;
    } else {
        const int r = bid - nx8 * 2;
        rowblk = nx8 + (r >> 1);
        colblk = r & 1;
    }
    const int row0 = rowblk * 128, col0 = colblk * 128;

    const int wave = tid >> 6, lane = tid & 63;
    const int wrow = (wave >> 1) * 64, wcol = (wave & 1) * 64;
    const int m16 = lane & 15, quad = lane >> 4;
    const int sr = tid >> 2;
    const int skc = (tid & 3) * 8;

    float4v acc[4][4];
#pragma unroll
    for (int i = 0; i < 4; i++)
#pragma unroll
        for (int j = 0; j < 4; j++) acc[i][j] = (float4v){0.f, 0.f, 0.f, 0.f};

#pragma unroll 1
    for (int pass = 0; pass < 2; pass++) {
        const ushort_t* A = pass ? A2 : A1;
        const ushort_t* W = pass ? W2 : W1;
        const int K = pass ? K2 : K1;
        if (!A) break;
        const int gr0 = row0 + sr, gr1 = row0 + sr + 64;
        const bool ok0 = gr0 < M, ok1 = gr1 < M;
        for (int k0 = 0; k0 < K; k0 += 32) {
            uint4 a0 = make_uint4(0, 0, 0, 0), a1 = make_uint4(0, 0, 0, 0);
            if (ok0) a0 = *(const uint4*)&A[(size_t)gr0 * K + k0 + skc];
            if (ok1) a1 = *(const uint4*)&A[(size_t)gr1 * K + k0 + skc];
            uint4 b0 = *(const uint4*)&W[(size_t)(col0 + sr) * K + k0 + skc];
            uint4 b1 = *(const uint4*)&W[(size_t)(col0 + sr + 64) * K + k0 + skc];
            __syncthreads();
            *(uint4*)&As[sr][skc] = a0;
            *(uint4*)&As[sr + 64][skc] = a1;
            *(uint4*)&Bs[sr][skc] = b0;
            *(uint4*)&Bs[sr + 64][skc] = b1;
            __syncthreads();
            short8 af[4], bf[4];
#pragma unroll
            for (int i = 0; i < 4; i++)
                af[i] = *(const short8*)&As[wrow + i * 16 + m16][quad * 8];
#pragma unroll
            for (int j = 0; j < 4; j++)
                bf[j] = *(const short8*)&Bs[wcol + j * 16 + m16][quad * 8];
#pragma unroll
            for (int i = 0; i < 4; i++)
#pragma unroll
                for (int j = 0; j < 4; j++)
                    acc[i][j] = __builtin_amdgcn_mfma_f32_16x16x32_bf16(
                        af[i], bf[j], acc[i][j], 0, 0, 0);
        }
    }

    const bool relu = flags & 1, f16out = flags & 2;
#pragma unroll
    for (int i = 0; i < 4; i++) {
        const int rbase = row0 + wrow + i * 16 + quad * 4;
#pragma unroll
        for (int r = 0; r < 4; r++) {
            const int row = rbase + r;
            if (row >= M) continue;
#pragma unroll
            for (int j = 0; j < 4; j++) {
                const int col = col0 + wcol + j * 16 + m16;
                float v = acc[i][j][r];
                if (Add) v += bf2f((unsigned int)Add[(size_t)row * 256 + col]);
                if (bias) v += bias[col];
                if (relu) v = fmaxf(v, 0.f);
                if (f16out) ((_Float16*)Cout)[(size_t)row * 256 + col] = (_Float16)v;
                else ((ushort_t*)Cout)[(size_t)row * 256 + col] = f2bf(v);
            }
        }
    }
}

// --------------------- batched fp32 -> bf16 convert ------------------------
struct CvtJobs {
    const float* src[14];
    ushort_t* dst[14];
    int n4[14];
    int cnt;
};

__global__ __launch_bounds__(256) void cvt_kernel(CvtJobs jb, int total4)
{
    int t = blockIdx.x * blockDim.x + threadIdx.x;
    if (t >= total4) return;
    int idx = t;
    for (int k = 0; k < jb.cnt; k++) {
        if (idx < jb.n4[k]) {
            float4 v = ((const float4*)jb.src[k])[idx];
            uint2 o;
            o.x = (unsigned int)f2bf(v.x) | ((unsigned int)f2bf(v.y) << 16);
            o.y = (unsigned int)f2bf(v.z) | ((unsigned int)f2bf(v.w) << 16);
            *(uint2*)(jb.dst[k] + (size_t)idx * 4) = o;
            return;
        }
        idx -= jb.n4[k];
    }
}

// -------------- decoder weight folding (one fused kernel) ------------------
__global__ __launch_bounds__(256) void fold_kernel(
    const float* __restrict__ Wd1, const float* __restrict__ bd1,
    const float* __restrict__ Wlin_s, const float* __restrict__ blin_s,
    const float* __restrict__ Wlin_t, const float* __restrict__ blin_t,
    float* __restrict__ Wc_s, float* __restrict__ Wc_t,
    float* __restrict__ bu, float* __restrict__ bv)
{
    const int b = blockIdx.x, t = threadIdx.x;
    if (b < 256) {
        float s = 0.f;
        for (int k = 0; k < 256; k++) s += Wd1[b * 512 + k] * Wlin_s[k * 256 + t];
        Wc_s[b * 256 + t] = s;
    } else if (b < 512) {
        const int h = b - 256;
        float s = 0.f;
        for (int k = 0; k < 256; k++) s += Wd1[h * 512 + 256 + k] * Wlin_t[k * 256 + t];
        Wc_t[h * 256 + t] = s;
    } else {
        float su = 0.f, sv = 0.f;
        for (int k = 0; k < 256; k++) {
            su += Wd1[t * 512 + k] * blin_s[k];
            sv += Wd1[t * 512 + 256 + k] * blin_t[k];
        }
        bu[t] = bd1[t] + su;
        bv[t] = sv;
    }
}

// --------------------------- CSR build -------------------------------------
__global__ void count_kernel(const int* __restrict__ src, const int* __restrict__ dst,
                             int* __restrict__ cnt_s, int* __restrict__ cnt_t, int E)
{
    int e = blockIdx.x * blockDim.x + threadIdx.x;
    if (e < E) {
        atomicAdd(&cnt_s[src[e]], 1);
        atomicAdd(&cnt_t[dst[e]], 1);
    }
}

__global__ __launch_bounds__(256) void psum_kernel(
    const int* __restrict__ cnt_s, const int* __restrict__ cnt_t,
    int* __restrict__ bsum_s, int* __restrict__ bsum_t, int nbS)
{
    const bool isS = (int)blockIdx.x < nbS;
    const int blk = isS ? blockIdx.x : blockIdx.x - nbS;
    const int N = isS ? NS : NT;
    const int* cnt = isS ? cnt_s : cnt_t;
    int* bsum = isS ? bsum_s : bsum_t;
    __shared__ int sdata[256];
    const int t = threadIdx.x;
    const int base = blk * 1024;
    int s = 0;
    for (int i = t; i < 1024; i += 256) {
        int idx = base + i;
        s += (idx < N) ? cnt[idx] : 0;
    }
    sdata[t] = s; __syncthreads();
    for (int off = 128; off > 0; off >>= 1) {
        if (t < off) sdata[t] += sdata[t + off];
        __syncthreads();
    }
    if (t == 0) bsum[blk] = sdata[0];
}

__global__ void sbsum_kernel(int* __restrict__ bsum_s, int* __restrict__ bsum_t,
                             int nbS, int nbT)
{
    if (threadIdx.x != 0) return;
    int* b = blockIdx.x ? bsum_t : bsum_s;
    int nb = blockIdx.x ? nbT : nbS;
    int run = 0;
    for (int i = 0; i < nb; i++) { int v = b[i]; b[i] = run; run += v; }
}

__global__ __launch_bounds__(256) void sblock_kernel(
    const int* __restrict__ cnt_s, const int* __restrict__ cnt_t,
    const int* __restrict__ bsum_s, const int* __restrict__ bsum_t,
    int* __restrict__ rowptr_s, int* __restrict__ rowptr_t, int nbS)
{
    const bool isS = (int)blockIdx.x < nbS;
    const int blk = isS ? blockIdx.x : blockIdx.x - nbS;
    const int N = isS ? NS : NT;
    const int* cnt = isS ? cnt_s : cnt_t;
    const int* bsum = isS ? bsum_s : bsum_t;
    int* rowptr = isS ? rowptr_s : rowptr_t;
    __shared__ int sc[256];
    const int t = threadIdx.x;
    const int base = blk * 1024 + t * 4;
    int v[4]; int s = 0;
#pragma unroll
    for (int j = 0; j < 4; j++) {
        int idx = base + j;
        v[j] = (idx < N) ? cnt[idx] : 0;
        s += v[j];
    }
    sc[t] = s; __syncthreads();
    for (int off = 1; off < 256; off <<= 1) {
        int add = (t >= off) ? sc[t - off] : 0;
        __syncthreads();
        sc[t] += add;
        __syncthreads();
    }
    int excl = sc[t] - s + bsum[blk];
#pragma unroll
    for (int j = 0; j < 4; j++) {
        int idx = base + j;
        if (idx < N) rowptr[idx] = excl;
        if (idx == N - 1) rowptr[N] = excl + v[j];
        excl += v[j];
    }
}

__global__ void binit_kernel(const int* __restrict__ rowptr_t,
                             const int* __restrict__ rowptr_s,
                             int* __restrict__ gcur_t, int* __restrict__ gcur_s)
{
    int t = threadIdx.x;
    if (t < NB_T) gcur_t[t] = rowptr_t[t << SH_T];
    if (t < NB_S) gcur_s[t] = rowptr_s[t << SH_S];
}

__global__ __launch_bounds__(256) void binA_kernel(
    const int* __restrict__ key, const int* __restrict__ val, int E,
    int nbins, int shift, int vbits,
    int* __restrict__ gcur, unsigned* __restrict__ stg)
{
    __shared__ unsigned bins[NB_S * BIN_CAP];
    __shared__ int lcnt[NB_S], gbase[NB_S];
    const int tid = threadIdx.x;
    const int base = blockIdx.x * CHUNK;
    for (int i = tid; i < nbins; i += 256) lcnt[i] = 0;
    __syncthreads();
    const unsigned lowmask = (1u << shift) - 1u;
#pragma unroll
    for (int k = 0; k < CHUNK / 256; k++) {
        int e = base + k * 256 + tid;
        if (e < E) {
            int kk = key[e];
            int b = kk >> shift;
            unsigned pk = (((unsigned)kk & lowmask) << vbits) | (unsigned)val[e];
            int c = atomicAdd(&lcnt[b], 1);
            if (c < BIN_CAP) bins[b * BIN_CAP + c] = pk;
            else { int p = atomicAdd(&gcur[b], 1); stg[p] = pk; }
        }
    }
    __syncthreads();
    if (tid < nbins) gbase[tid] = atomicAdd(&gcur[tid], min(lcnt[tid], BIN_CAP));
    __syncthreads();
    for (int b = 0; b < nbins; b++) {
        int c = min(lcnt[b], BIN_CAP);
        for (int i = tid; i < c; i += 256) stg[gbase[b] + i] = bins[b * BIN_CAP + i];
    }
}

__global__ __launch_bounds__(256) void binB_kernel(
    const unsigned* __restrict__ stg, const int* __restrict__ rowptr,
    int N, int node_per, int vbits, int* __restrict__ colout)
{
    __shared__ int cur[1024];
    const int tid = threadIdx.x;
    const int node0 = blockIdx.x * node_per;
    const int nn = min(node_per, N - node0);
    for (int i = tid; i < nn; i += 256) cur[i] = rowptr[node0 + i];
    const int estart = rowptr[node0];
    const int eend = rowptr[node0 + nn];
    __syncthreads();
    const unsigned vmask = (1u << vbits) - 1u;
    for (int i = estart + tid; i < eend; i += 256) {
        unsigned v = stg[i];
        int kl = (int)(v >> vbits);
        int pos = atomicAdd(&cur[kl], 1);
        colout[pos] = (int)(v & vmask);
    }
}

// ------------------- gather mean (bf16 rows, fp32 accum) -------------------
__global__ __launch_bounds__(256) void gather_mean_kernel(
    const ushort_t* __restrict__ X, const int* __restrict__ rowptr,
    const int* __restrict__ cnt, const int* __restrict__ col,
    ushort_t* __restrict__ out, int N)
{
    const int node = blockIdx.x * 8 + (threadIdx.x >> 5);
    const int c = (threadIdx.x & 31) * 8;
    if (node >= N) return;
    const int beg = rowptr[node];
    const int deg = cnt[node];
    const int end = beg + deg;
    float a[8] = {0, 0, 0, 0, 0, 0, 0, 0};
    float b[8] = {0, 0, 0, 0, 0, 0, 0, 0};
    int i = beg;
    for (; i + 1 < end; i += 2) {
        uint4 v = *(const uint4*)&X[(size_t)col[i] * 256 + c];
        uint4 w = *(const uint4*)&X[(size_t)col[i + 1] * 256 + c];
        a[0] += bf2f(v.x & 0xffff); a[1] += bf2f(v.x >> 16);
        a[2] += bf2f(v.y & 0xffff); a[3] += bf2f(v.y >> 16);
        a[4] += bf2f(v.z & 0xffff); a[5] += bf2f(v.z >> 16);
        a[6] += bf2f(v.w & 0xffff); a[7] += bf2f(v.w >> 16);
        b[0] += bf2f(w.x & 0xffff); b[1] += bf2f(w.x >> 16);
        b[2] += bf2f(w.y & 0xffff); b[3] += bf2f(w.y >> 16);
        b[4] += bf2f(w.z & 0xffff); b[5] += bf2f(w.z >> 16);
        b[6] += bf2f(w.w & 0xffff); b[7] += bf2f(w.w >> 16);
    }
    if (i < end) {
        uint4 v = *(const uint4*)&X[(size_t)col[i] * 256 + c];
        a[0] += bf2f(v.x & 0xffff); a[1] += bf2f(v.x >> 16);
        a[2] += bf2f(v.y & 0xffff); a[3] += bf2f(v.y >> 16);
        a[4] += bf2f(v.z & 0xffff); a[5] += bf2f(v.z >> 16);
        a[6] += bf2f(v.w & 0xffff); a[7] += bf2f(v.w >> 16);
    }
    float inv = 1.f / fmaxf((float)deg, 1.f);
    uint4 o;
    o.x = (unsigned int)f2bf((a[0] + b[0]) * inv) | ((unsigned int)f2bf((a[1] + b[1]) * inv) << 16);
    o.y = (unsigned int)f2bf((a[2] + b[2]) * inv) | ((unsigned int)f2bf((a[3] + b[3]) * inv) << 16);
    o.z = (unsigned int)f2bf((a[4] + b[4]) * inv) | ((unsigned int)f2bf((a[5] + b[5]) * inv) << 16);
    o.w = (unsigned int)f2bf((a[6] + b[6]) * inv) | ((unsigned int)f2bf((a[7] + b[7]) * inv) << 16);
    *(uint4*)&out[(size_t)node * 256 + c] = o;
}

// ------------------------- per-edge score (fp16 U/V) -----------------------
__global__ __launch_bounds__(256) void edge_score_kernel(
    const _Float16* __restrict__ U, const _Float16* __restrict__ V,
    const int* __restrict__ ls, const int* __restrict__ ld,
    const float* __restrict__ Wd2, const float* __restrict__ bd2,
    float* __restrict__ out, int EL)
{
    const int l32 = threadIdx.x & 31;
    const int e = blockIdx.x * 8 + (threadIdx.x >> 5);
    if (e >= EL) return;
    const int c = l32 * 8;
    half8v u = *(const half8v*)&U[(size_t)ls[e] * 256 + c];
    half8v v = *(const half8v*)&V[(size_t)ld[e] * 256 + c];
    float4 w0 = *(const float4*)&Wd2[c];
    float4 w1 = *(const float4*)&Wd2[c + 4];
    float s = fmaxf((float)u[0] + (float)v[0], 0.f) * w0.x
            + fmaxf((float)u[1] + (float)v[1], 0.f) * w0.y
            + fmaxf((float)u[2] + (float)v[2], 0.f) * w0.z
            + fmaxf((float)u[3] + (float)v[3], 0.f) * w0.w
            + fmaxf((float)u[4] + (float)v[4], 0.f) * w1.x
            + fmaxf((float)u[5] + (float)v[5], 0.f) * w1.y
            + fmaxf((float)u[6] + (float)v[6], 0.f) * w1.z
            + fmaxf((float)u[7] + (float)v[7], 0.f) * w1.w;
#pragma unroll
    for (int m = 16; m >= 1; m >>= 1) s += __shfl_xor(s, m, 64);
    if (l32 == 0) out[e] = s + bd2[0];
}

// ---------------------------------------------------------------------------
extern "C" void kernel_launch(void* const* d_in, const int* in_sizes, int n_in,
                              void* d_out, int out_size, void* d_ws, size_t ws_size,
                              hipStream_t stream)
{
    const float* x_sotu  = (const float*)d_in[0];
    const float* x_taxon = (const float*)d_in[1];
    const int* edge_src  = (const int*)d_in[2];
    const int* edge_dst  = (const int*)d_in[3];
    const int* label_src = (const int*)d_in[4];
    const int* label_dst = (const int*)d_in[5];
    const float* Wl1_st = (const float*)d_in[6];
    const float* bl1_st = (const float*)d_in[7];
    const float* Wr1_st = (const float*)d_in[8];
    const float* Wl1_ts = (const float*)d_in[9];
    const float* bl1_ts = (const float*)d_in[10];
    const float* Wr1_ts = (const float*)d_in[11];
    const float* Wl2_st = (const float*)d_in[12];
    const float* bl2_st = (const float*)d_in[13];
    const float* Wr2_st = (const float*)d_in[14];
    const float* Wl2_ts = (const float*)d_in[15];
    const float* bl2_ts = (const float*)d_in[16];
    const float* Wr2_ts = (const float*)d_in[17];
    const float* Wlin_s = (const float*)d_in[18];
    const float* blin_s = (const float*)d_in[19];
    const float* Wlin_t = (const float*)d_in[20];
    const float* blin_t = (const float*)d_in[21];
    const float* Wd1 = (const float*)d_in[22];
    const float* bd1 = (const float*)d_in[23];
    const float* Wd2 = (const float*)d_in[24];
    const float* bd2 = (const float*)d_in[25];

    // -------- workspace layout --------
    int* wi = (int*)d_ws;
    size_t io = 0;
    int* cnt_s   = wi + io; io += NS;
    int* cnt_t   = wi + io; io += NT;
    int* rowptr_s = wi + io; io += NS + 8;
    int* rowptr_t = wi + io; io += NT + 8;
    int* col_s   = wi + io; io += E_EDGES;
    int* col_t   = wi + io; io += E_EDGES;
    unsigned* stg_s = (unsigned*)(wi + io); io += E_EDGES;
    unsigned* stg_t = (unsigned*)(wi + io); io += E_EDGES;
    int* bsum_s  = wi + io; io += 128;
    int* bsum_t  = wi + io; io += 128;
    int* gcur_t  = wi + io; io += 128;
    int* gcur_s  = wi + io; io += 128;
    io = (io + 63) & ~(size_t)63;

    ushort_t* wb = (ushort_t*)(wi + io);
    size_t bo = 0;
    ushort_t* m_s  = wb + bo; bo += (size_t)NS * H;   // U (fp16) overlays m_s
    ushort_t* h1_s = wb + bo; bo += (size_t)NS * H;
    ushort_t* m_t  = wb + bo; bo += (size_t)NT * H;   // V (fp16) overlays m_t
    ushort_t* h1_t = wb + bo; bo += (size_t)NT * H;
    ushort_t* h2_s = wb + bo; bo += (size_t)NS * H;
    ushort_t* h2_t = wb + bo; bo += (size_t)NT * H;
    ushort_t* xs_b = wb + bo; bo += (size_t)NS * DS;
    ushort_t* xt_b = wb + bo; bo += (size_t)NT * DT;
    ushort_t* Pt   = wb + bo; bo += (size_t)NT * H;
    ushort_t* wb_l1st = wb + bo; bo += H * DS;
    ushort_t* wb_r1st = wb + bo; bo += H * DT;
    ushort_t* wb_l1ts = wb + bo; bo += H * DT;
    ushort_t* wb_r1ts = wb + bo; bo += H * DS;
    ushort_t* wb_l2st = wb + bo; bo += H * H;
    ushort_t* wb_r2st = wb + bo; bo += H * H;
    ushort_t* wb_l2ts = wb + bo; bo += H * H;
    ushort_t* wb_r2ts = wb + bo; bo += H * H;
    ushort_t* wcb_s   = wb + bo; bo += H * H;
    ushort_t* wcb_t   = wb + bo; bo += H * H;
    bo = (bo + 7) & ~(size_t)7;

    float* wf = (float*)(wb + bo);
    size_t fo = 0;
    float* Wc_s = wf + fo; fo += H * H;
    float* Wc_t = wf + fo; fo += H * H;
    float* bu   = wf + fo; fo += 256;
    float* bv   = wf + fo; fo += 256;

    _Float16* U = (_Float16*)m_s;
    _Float16* V = (_Float16*)m_t;

    const dim3 blk(256);
    auto mg = [](int M) { return dim3(((M + 127) / 128) * 2); };
    const int nbS = (NS + 1023) / 1024;   // 98
    const int nbT = (NT + 1023) / 1024;   // 20
    const int nA = (E_EDGES + CHUNK - 1) / CHUNK;

    // ---- decoder weight folding ----
    fold_kernel<<<513, blk, 0, stream>>>(Wd1, bd1, Wlin_s, blin_s, Wlin_t, blin_t,
                                         Wc_s, Wc_t, bu, bv);

    // ---- batched fp32->bf16 conversion ----
    {
        CvtJobs jb; int c = 0, total4 = 0;
        auto addj = [&](const float* s, ushort_t* d, int n) {
            jb.src[c] = s; jb.dst[c] = d; jb.n4[c] = n / 4; total4 += n / 4; c++;
        };
        addj(x_sotu, xs_b, NS * DS);
        addj(x_taxon, xt_b, NT * DT);
        addj(Wl1_st, wb_l1st, H * DS);
        addj(Wr1_st, wb_r1st, H * DT);
        addj(Wl1_ts, wb_l1ts, H * DT);
        addj(Wr1_ts, wb_r1ts, H * DS);
        addj(Wl2_st, wb_l2st, H * H);
        addj(Wr2_st, wb_r2st, H * H);
        addj(Wl2_ts, wb_l2ts, H * H);
        addj(Wr2_ts, wb_r2ts, H * H);
        addj(Wc_s, wcb_s, H * H);
        addj(Wc_t, wcb_t, H * H);
        jb.cnt = c;
        cvt_kernel<<<(total4 + 255) / 256, blk, 0, stream>>>(jb, total4);
    }

    // ---- CSR build: count -> scan -> binned two-pass fill ----
    hipMemsetAsync(cnt_s, 0, (size_t)(NS + NT) * sizeof(int), stream);
    count_kernel<<<(E_EDGES + 255) / 256, blk, 0, stream>>>(edge_src, edge_dst,
                                                            cnt_s, cnt_t, E_EDGES);
    psum_kernel<<<nbS + nbT, blk, 0, stream>>>(cnt_s, cnt_t, bsum_s, bsum_t, nbS);
    sbsum_kernel<<<2, 64, 0, stream>>>(bsum_s, bsum_t, nbS, nbT);
    sblock_kernel<<<nbS + nbT, blk, 0, stream>>>(cnt_s, cnt_t, bsum_s, bsum_t,
                                                 rowptr_s, rowptr_t, nbS);
    binit_kernel<<<1, blk, 0, stream>>>(rowptr_t, rowptr_s, gcur_t, gcur_s);
    binA_kernel<<<nA, blk, 0, stream>>>(edge_dst, edge_src, E_EDGES,
                                        NB_T, SH_T, VB_T, gcur_t, stg_t);
    binA_kernel<<<nA, blk, 0, stream>>>(edge_src, edge_dst, E_EDGES,
                                        NB_S, SH_S, VB_S, gcur_s, stg_s);
    binB_kernel<<<NB_T, blk, 0, stream>>>(stg_t, rowptr_t, NT, 1 << SH_T, VB_T, col_t);
    binB_kernel<<<NB_S, blk, 0, stream>>>(stg_s, rowptr_s, NS, 1 << SH_S, VB_S, col_s);

    // ---- layer 1 ----
    mgemm_kernel<<<mg(NT), blk, 0, stream>>>(xt_b, wb_l1ts, DT, nullptr, nullptr, 0,
                                             nullptr, nullptr, Pt, NT, 0);
    gather_mean_kernel<<<(NT + 7) / 8, blk, 0, stream>>>(
        xs_b, rowptr_t, cnt_t, col_t, m_t, NT);
    gather_mean_kernel<<<(NS + 7) / 8, blk, 0, stream>>>(
        Pt, rowptr_s, cnt_s, col_s, m_s, NS);
    mgemm_kernel<<<mg(NT), blk, 0, stream>>>(m_t, wb_l1st, H, xt_b, wb_r1st, DT,
                                             nullptr, bl1_st, h1_t, NT, 1);
    mgemm_kernel<<<mg(NS), blk, 0, stream>>>(xs_b, wb_r1ts, DS, nullptr, nullptr, 0,
                                             m_s, bl1_ts, h1_s, NS, 1);

    // ---- layer 2 ----
    mgemm_kernel<<<mg(NT), blk, 0, stream>>>(h1_t, wb_l2ts, H, nullptr, nullptr, 0,
                                             nullptr, nullptr, Pt, NT, 0);
    gather_mean_kernel<<<(NT + 7) / 8, blk, 0, stream>>>(
        h1_s, rowptr_t, cnt_t, col_t, m_t, NT);
    gather_mean_kernel<<<(NS + 7) / 8, blk, 0, stream>>>(
        Pt, rowptr_s, cnt_s, col_s, m_s, NS);
    mgemm_kernel<<<mg(NT), blk, 0, stream>>>(m_t, wb_l2st, H, h1_t, wb_r2st, H,
                                             nullptr, bl2_st, h2_t, NT, 1);
    mgemm_kernel<<<mg(NS), blk, 0, stream>>>(h1_s, wb_r2ts, H, nullptr, nullptr, 0,
                                             m_s, bl2_ts, h2_s, NS, 1);

    // ---- decoder: U/V node potentials (fp16 out) + per-edge reduce ----
    mgemm_kernel<<<mg(NS), blk, 0, stream>>>(h2_s, wcb_s, H, nullptr, nullptr, 0,
                                             nullptr, bu, U, NS, 2);
    mgemm_kernel<<<mg(NT), blk, 0, stream>>>(h2_t, wcb_t, H, nullptr, nullptr, 0,
                                             nullptr, bv, V, NT, 2);
    edge_score_kernel<<<(EL_EDGES + 7) / 8, blk, 0, stream>>>(
        U, V, label_src, label_dst, Wd2, bd2, (float*)d_out, EL_EDGES);
}

// Round 11
// 973.402 us; speedup vs baseline: 1.2237x; 1.0120x over previous
//
#include <hip/hip_runtime.h>

// ---------------------------------------------------------------------------
// Hetero GraphSAGE (2 layers) + edge decoder.
// R1: CSR-gather aggregation. R4: algebraic restructure (U/V decoder split,
//     weight folding, project-before-aggregate). FLOP 1.23e11 -> 5.3e10.
// R5: bf16 MFMA GEMMs + bf16 activations. R6: fp16 U/V, fused CSR aux.
// R8: two-pass LDS-binned CSR fill (108MB scattered writes -> ~14MB). 994us.
// R9 FAILED: 64x256 tile + prefetch (two variables at once; tile was toxic).
// R10: XCD-paired swizzle: FETCH 76->51.5MB as predicted, dur ~flat ->
//     PROVED mgemm is latency-bound, not HBM-bound (MfmaUtil 5.3%).
// R11: register prefetch ONLY, on the proven 128x128 tile + swizzle:
//     tile k+1 loads issued right after store-barrier, hidden by the 16-MFMA
//     phase. +16 VGPR (72->88), still 3 waves/SIMD — no occupancy cliff.
// ---------------------------------------------------------------------------

constexpr int NS = 100000, NT = 20000;
constexpr int E_EDGES = 800000, EL_EDGES = 200000;
constexpr int DS = 256, DT = 128, H = 256;

constexpr int NB_T = 79, SH_T = 8, VB_T = 17;
constexpr int NB_S = 98, SH_S = 10, VB_S = 15;
constexpr int BIN_CAP = 96, CHUNK = 2048;

typedef __attribute__((ext_vector_type(8))) short short8;
typedef __attribute__((ext_vector_type(4))) float float4v;
typedef __attribute__((ext_vector_type(8))) _Float16 half8v;
typedef unsigned short ushort_t;

__device__ __forceinline__ float bf2f(unsigned int u) {
    union { unsigned int i; float f; } x; x.i = u << 16; return x.f;
}
__device__ __forceinline__ unsigned short f2bf(float f) {
    union { float f; unsigned int i; } x; x.f = f;
    unsigned int r = x.i + 0x7FFFu + ((x.i >> 16) & 1u);   // RNE
    return (unsigned short)(r >> 16);
}

// --------------------------- MFMA GEMM -------------------------------------
// C[M,256] = op( A1@W1^T [+ A2@W2^T] [+ Add] [+ bias] )
// 128x128 tile, BK=32, LDS stride 40 (R8-proven), XCD-paired swizzle (R10),
// register prefetch of tile k+1 issued before the MFMA phase of tile k (R11).
// flags: 1 = relu, 2 = fp16 output (else bf16)
__global__ __launch_bounds__(256) void mgemm_kernel(
    const ushort_t* __restrict__ A1, const ushort_t* __restrict__ W1, int K1,
    const ushort_t* __restrict__ A2, const ushort_t* __restrict__ W2, int K2,
    const ushort_t* __restrict__ Add, const float* __restrict__ bias,
    void* __restrict__ Cout, int M, int flags)
{
    __shared__ ushort_t As[128][40];
    __shared__ ushort_t Bs[128][40];
    const int tid = threadIdx.x;

    // ---- XCD-paired swizzle: bid -> (rowblk, colblk) ----
    const int nx = (M + 127) >> 7;          // row-blocks
    const int nx8 = nx & ~7;                // swizzled region (multiple of 8)
    const int bid = blockIdx.x;
    int rowblk, colblk;
    if (bid < nx8 * 2) {
        const int group = bid >> 4;         // 16 blocks per group
        const int xcd = bid & 7;
        const int half = (bid >> 3) & 1;
        rowblk = group * 8 + xcd;
        colblk = half;
    } else {
        const int r = bid - nx8 * 2;
        rowblk = nx8 + (r >> 1);
        colblk = r & 1;
    }
    const int row0 = rowblk * 128, col0 = colblk * 128;

    const int wave = tid >> 6, lane = tid & 63;
    const int wrow = (wave >> 1) * 64, wcol = (wave & 1) * 64;
    const int m16 = lane & 15, quad = lane >> 4;
    const int sr = tid >> 2;
    const int skc = (tid & 3) * 8;

    float4v acc[4][4];
#pragma unroll
    for (int i = 0; i < 4; i++)
#pragma unroll
        for (int j = 0; j < 4; j++) acc[i][j] = (float4v){0.f, 0.f, 0.f, 0.f};

#pragma unroll 1
    for (int pass = 0; pass < 2; pass++) {
        const ushort_t* A = pass ? A2 : A1;
        const ushort_t* W = pass ? W2 : W1;
        const int K = pass ? K2 : K1;
        if (!A) break;
        const int gr0 = row0 + sr, gr1 = row0 + sr + 64;
        const bool ok0 = gr0 < M, ok1 = gr1 < M;
        const ushort_t* Ap0 = A + (size_t)gr0 * K + skc;
        const ushort_t* Ap1 = A + (size_t)gr1 * K + skc;
        const ushort_t* Wp0 = W + (size_t)(col0 + sr) * K + skc;
        const ushort_t* Wp1 = W + (size_t)(col0 + sr + 64) * K + skc;

        // preload tile 0
        uint4 a0 = make_uint4(0, 0, 0, 0), a1 = make_uint4(0, 0, 0, 0);
        if (ok0) a0 = *(const uint4*)Ap0;
        if (ok1) a1 = *(const uint4*)Ap1;
        uint4 b0 = *(const uint4*)Wp0;
        uint4 b1 = *(const uint4*)Wp1;

        for (int k0 = 0; k0 < K; k0 += 32) {
            __syncthreads();                 // prev iter done reading LDS
            *(uint4*)&As[sr][skc] = a0;
            *(uint4*)&As[sr + 64][skc] = a1;
            *(uint4*)&Bs[sr][skc] = b0;
            *(uint4*)&Bs[sr + 64][skc] = b1;
            __syncthreads();                 // LDS ready
            if (k0 + 32 < K) {               // prefetch tile k+1 (hidden by MFMAs)
                a0 = make_uint4(0, 0, 0, 0); a1 = make_uint4(0, 0, 0, 0);
                if (ok0) a0 = *(const uint4*)(Ap0 + k0 + 32);
                if (ok1) a1 = *(const uint4*)(Ap1 + k0 + 32);
                b0 = *(const uint4*)(Wp0 + k0 + 32);
                b1 = *(const uint4*)(Wp1 + k0 + 32);
            }
            short8 af[4], bf[4];
#pragma unroll
            for (int i = 0; i < 4; i++)
                af[i] = *(const short8*)&As[wrow + i * 16 + m16][quad * 8];
#pragma unroll
            for (int j = 0; j < 4; j++)
                bf[j] = *(const short8*)&Bs[wcol + j * 16 + m16][quad * 8];
#pragma unroll
            for (int i = 0; i < 4; i++)
#pragma unroll
                for (int j = 0; j < 4; j++)
                    acc[i][j] = __builtin_amdgcn_mfma_f32_16x16x32_bf16(
                        af[i], bf[j], acc[i][j], 0, 0, 0);
        }
    }

    const bool relu = flags & 1, f16out = flags & 2;
#pragma unroll
    for (int i = 0; i < 4; i++) {
        const int rbase = row0 + wrow + i * 16 + quad * 4;
#pragma unroll
        for (int r = 0; r < 4; r++) {
            const int row = rbase + r;
            if (row >= M) continue;
#pragma unroll
            for (int j = 0; j < 4; j++) {
                const int col = col0 + wcol + j * 16 + m16;
                float v = acc[i][j][r];
                if (Add) v += bf2f((unsigned int)Add[(size_t)row * 256 + col]);
                if (bias) v += bias[col];
                if (relu) v = fmaxf(v, 0.f);
                if (f16out) ((_Float16*)Cout)[(size_t)row * 256 + col] = (_Float16)v;
                else ((ushort_t*)Cout)[(size_t)row * 256 + col] = f2bf(v);
            }
        }
    }
}

// --------------------- batched fp32 -> bf16 convert ------------------------
struct CvtJobs {
    const float* src[14];
    ushort_t* dst[14];
    int n4[14];
    int cnt;
};

__global__ __launch_bounds__(256) void cvt_kernel(CvtJobs jb, int total4)
{
    int t = blockIdx.x * blockDim.x + threadIdx.x;
    if (t >= total4) return;
    int idx = t;
    for (int k = 0; k < jb.cnt; k++) {
        if (idx < jb.n4[k]) {
            float4 v = ((const float4*)jb.src[k])[idx];
            uint2 o;
            o.x = (unsigned int)f2bf(v.x) | ((unsigned int)f2bf(v.y) << 16);
            o.y = (unsigned int)f2bf(v.z) | ((unsigned int)f2bf(v.w) << 16);
            *(uint2*)(jb.dst[k] + (size_t)idx * 4) = o;
            return;
        }
        idx -= jb.n4[k];
    }
}

// -------------- decoder weight folding (one fused kernel) ------------------
__global__ __launch_bounds__(256) void fold_kernel(
    const float* __restrict__ Wd1, const float* __restrict__ bd1,
    const float* __restrict__ Wlin_s, const float* __restrict__ blin_s,
    const float* __restrict__ Wlin_t, const float* __restrict__ blin_t,
    float* __restrict__ Wc_s, float* __restrict__ Wc_t,
    float* __restrict__ bu, float* __restrict__ bv)
{
    const int b = blockIdx.x, t = threadIdx.x;
    if (b < 256) {
        float s = 0.f;
        for (int k = 0; k < 256; k++) s += Wd1[b * 512 + k] * Wlin_s[k * 256 + t];
        Wc_s[b * 256 + t] = s;
    } else if (b < 512) {
        const int h = b - 256;
        float s = 0.f;
        for (int k = 0; k < 256; k++) s += Wd1[h * 512 + 256 + k] * Wlin_t[k * 256 + t];
        Wc_t[h * 256 + t] = s;
    } else {
        float su = 0.f, sv = 0.f;
        for (int k = 0; k < 256; k++) {
            su += Wd1[t * 512 + k] * blin_s[k];
            sv += Wd1[t * 512 + 256 + k] * blin_t[k];
        }
        bu[t] = bd1[t] + su;
        bv[t] = sv;
    }
}

// --------------------------- CSR build -------------------------------------
__global__ void count_kernel(const int* __restrict__ src, const int* __restrict__ dst,
                             int* __restrict__ cnt_s, int* __restrict__ cnt_t, int E)
{
    int e = blockIdx.x * blockDim.x + threadIdx.x;
    if (e < E) {
        atomicAdd(&cnt_s[src[e]], 1);
        atomicAdd(&cnt_t[dst[e]], 1);
    }
}

__global__ __launch_bounds__(256) void psum_kernel(
    const int* __restrict__ cnt_s, const int* __restrict__ cnt_t,
    int* __restrict__ bsum_s, int* __restrict__ bsum_t, int nbS)
{
    const bool isS = (int)blockIdx.x < nbS;
    const int blk = isS ? blockIdx.x : blockIdx.x - nbS;
    const int N = isS ? NS : NT;
    const int* cnt = isS ? cnt_s : cnt_t;
    int* bsum = isS ? bsum_s : bsum_t;
    __shared__ int sdata[256];
    const int t = threadIdx.x;
    const int base = blk * 1024;
    int s = 0;
    for (int i = t; i < 1024; i += 256) {
        int idx = base + i;
        s += (idx < N) ? cnt[idx] : 0;
    }
    sdata[t] = s; __syncthreads();
    for (int off = 128; off > 0; off >>= 1) {
        if (t < off) sdata[t] += sdata[t + off];
        __syncthreads();
    }
    if (t == 0) bsum[blk] = sdata[0];
}

__global__ void sbsum_kernel(int* __restrict__ bsum_s, int* __restrict__ bsum_t,
                             int nbS, int nbT)
{
    if (threadIdx.x != 0) return;
    int* b = blockIdx.x ? bsum_t : bsum_s;
    int nb = blockIdx.x ? nbT : nbS;
    int run = 0;
    for (int i = 0; i < nb; i++) { int v = b[i]; b[i] = run; run += v; }
}

__global__ __launch_bounds__(256) void sblock_kernel(
    const int* __restrict__ cnt_s, const int* __restrict__ cnt_t,
    const int* __restrict__ bsum_s, const int* __restrict__ bsum_t,
    int* __restrict__ rowptr_s, int* __restrict__ rowptr_t, int nbS)
{
    const bool isS = (int)blockIdx.x < nbS;
    const int blk = isS ? blockIdx.x : blockIdx.x - nbS;
    const int N = isS ? NS : NT;
    const int* cnt = isS ? cnt_s : cnt_t;
    const int* bsum = isS ? bsum_s : bsum_t;
    int* rowptr = isS ? rowptr_s : rowptr_t;
    __shared__ int sc[256];
    const int t = threadIdx.x;
    const int base = blk * 1024 + t * 4;
    int v[4]; int s = 0;
#pragma unroll
    for (int j = 0; j < 4; j++) {
        int idx = base + j;
        v[j] = (idx < N) ? cnt[idx] : 0;
        s += v[j];
    }
    sc[t] = s; __syncthreads();
    for (int off = 1; off < 256; off <<= 1) {
        int add = (t >= off) ? sc[t - off] : 0;
        __syncthreads();
        sc[t] += add;
        __syncthreads();
    }
    int excl = sc[t] - s + bsum[blk];
#pragma unroll
    for (int j = 0; j < 4; j++) {
        int idx = base + j;
        if (idx < N) rowptr[idx] = excl;
        if (idx == N - 1) rowptr[N] = excl + v[j];
        excl += v[j];
    }
}

__global__ void binit_kernel(const int* __restrict__ rowptr_t,
                             const int* __restrict__ rowptr_s,
                             int* __restrict__ gcur_t, int* __restrict__ gcur_s)
{
    int t = threadIdx.x;
    if (t < NB_T) gcur_t[t] = rowptr_t[t << SH_T];
    if (t < NB_S) gcur_s[t] = rowptr_s[t << SH_S];
}

__global__ __launch_bounds__(256) void binA_kernel(
    const int* __restrict__ key, const int* __restrict__ val, int E,
    int nbins, int shift, int vbits,
    int* __restrict__ gcur, unsigned* __restrict__ stg)
{
    __shared__ unsigned bins[NB_S * BIN_CAP];
    __shared__ int lcnt[NB_S], gbase[NB_S];
    const int tid = threadIdx.x;
    const int base = blockIdx.x * CHUNK;
    for (int i = tid; i < nbins; i += 256) lcnt[i] = 0;
    __syncthreads();
    const unsigned lowmask = (1u << shift) - 1u;
#pragma unroll
    for (int k = 0; k < CHUNK / 256; k++) {
        int e = base + k * 256 + tid;
        if (e < E) {
            int kk = key[e];
            int b = kk >> shift;
            unsigned pk = (((unsigned)kk & lowmask) << vbits) | (unsigned)val[e];
            int c = atomicAdd(&lcnt[b], 1);
            if (c < BIN_CAP) bins[b * BIN_CAP + c] = pk;
            else { int p = atomicAdd(&gcur[b], 1); stg[p] = pk; }
        }
    }
    __syncthreads();
    if (tid < nbins) gbase[tid] = atomicAdd(&gcur[tid], min(lcnt[tid], BIN_CAP));
    __syncthreads();
    for (int b = 0; b < nbins; b++) {
        int c = min(lcnt[b], BIN_CAP);
        for (int i = tid; i < c; i += 256) stg[gbase[b] + i] = bins[b * BIN_CAP + i];
    }
}

__global__ __launch_bounds__(256) void binB_kernel(
    const unsigned* __restrict__ stg, const int* __restrict__ rowptr,
    int N, int node_per, int vbits, int* __restrict__ colout)
{
    __shared__ int cur[1024];
    const int tid = threadIdx.x;
    const int node0 = blockIdx.x * node_per;
    const int nn = min(node_per, N - node0);
    for (int i = tid; i < nn; i += 256) cur[i] = rowptr[node0 + i];
    const int estart = rowptr[node0];
    const int eend = rowptr[node0 + nn];
    __syncthreads();
    const unsigned vmask = (1u << vbits) - 1u;
    for (int i = estart + tid; i < eend; i += 256) {
        unsigned v = stg[i];
        int kl = (int)(v >> vbits);
        int pos = atomicAdd(&cur[kl], 1);
        colout[pos] = (int)(v & vmask);
    }
}

// ------------------- gather mean (bf16 rows, fp32 accum) -------------------
__global__ __launch_bounds__(256) void gather_mean_kernel(
    const ushort_t* __restrict__ X, const int* __restrict__ rowptr,
    const int* __restrict__ cnt, const int* __restrict__ col,
    ushort_t* __restrict__ out, int N)
{
    const int node = blockIdx.x * 8 + (threadIdx.x >> 5);
    const int c = (threadIdx.x & 31) * 8;
    if (node >= N) return;
    const int beg = rowptr[node];
    const int deg = cnt[node];
    const int end = beg + deg;
    float a[8] = {0, 0, 0, 0, 0, 0, 0, 0};
    float b[8] = {0, 0, 0, 0, 0, 0, 0, 0};
    int i = beg;
    for (; i + 1 < end; i += 2) {
        uint4 v = *(const uint4*)&X[(size_t)col[i] * 256 + c];
        uint4 w = *(const uint4*)&X[(size_t)col[i + 1] * 256 + c];
        a[0] += bf2f(v.x & 0xffff); a[1] += bf2f(v.x >> 16);
        a[2] += bf2f(v.y & 0xffff); a[3] += bf2f(v.y >> 16);
        a[4] += bf2f(v.z & 0xffff); a[5] += bf2f(v.z >> 16);
        a[6] += bf2f(v.w & 0xffff); a[7] += bf2f(v.w >> 16);
        b[0] += bf2f(w.x & 0xffff); b[1] += bf2f(w.x >> 16);
        b[2] += bf2f(w.y & 0xffff); b[3] += bf2f(w.y >> 16);
        b[4] += bf2f(w.z & 0xffff); b[5] += bf2f(w.z >> 16);
        b[6] += bf2f(w.w & 0xffff); b[7] += bf2f(w.w >> 16);
    }
    if (i < end) {
        uint4 v = *(const uint4*)&X[(size_t)col[i] * 256 + c];
        a[0] += bf2f(v.x & 0xffff); a[1] += bf2f(v.x >> 16);
        a[2] += bf2f(v.y & 0xffff); a[3] += bf2f(v.y >> 16);
        a[4] += bf2f(v.z & 0xffff); a[5] += bf2f(v.z >> 16);
        a[6] += bf2f(v.w & 0xffff); a[7] += bf2f(v.w >> 16);
    }
    float inv = 1.f / fmaxf((float)deg, 1.f);
    uint4 o;
    o.x = (unsigned int)f2bf((a[0] + b[0]) * inv) | ((unsigned int)f2bf((a[1] + b[1]) * inv) << 16);
    o.y = (unsigned int)f2bf((a[2] + b[2]) * inv) | ((unsigned int)f2bf((a[3] + b[3]) * inv) << 16);
    o.z = (unsigned int)f2bf((a[4] + b[4]) * inv) | ((unsigned int)f2bf((a[5] + b[5]) * inv) << 16);
    o.w = (unsigned int)f2bf((a[6] + b[6]) * inv) | ((unsigned int)f2bf((a[7] + b[7]) * inv) << 16);
    *(uint4*)&out[(size_t)node * 256 + c] = o;
}

// ------------------------- per-edge score (fp16 U/V) -----------------------
__global__ __launch_bounds__(256) void edge_score_kernel(
    const _Float16* __restrict__ U, const _Float16* __restrict__ V,
    const int* __restrict__ ls, const int* __restrict__ ld,
    const float* __restrict__ Wd2, const float* __restrict__ bd2,
    float* __restrict__ out, int EL)
{
    const int l32 = threadIdx.x & 31;
    const int e = blockIdx.x * 8 + (threadIdx.x >> 5);
    if (e >= EL) return;
    const int c = l32 * 8;
    half8v u = *(const half8v*)&U[(size_t)ls[e] * 256 + c];
    half8v v = *(const half8v*)&V[(size_t)ld[e] * 256 + c];
    float4 w0 = *(const float4*)&Wd2[c];
    float4 w1 = *(const float4*)&Wd2[c + 4];
    float s = fmaxf((float)u[0] + (float)v[0], 0.f) * w0.x
            + fmaxf((float)u[1] + (float)v[1], 0.f) * w0.y
            + fmaxf((float)u[2] + (float)v[2], 0.f) * w0.z
            + fmaxf((float)u[3] + (float)v[3], 0.f) * w0.w
            + fmaxf((float)u[4] + (float)v[4], 0.f) * w1.x
            + fmaxf((float)u[5] + (float)v[5], 0.f) * w1.y
            + fmaxf((float)u[6] + (float)v[6], 0.f) * w1.z
            + fmaxf((float)u[7] + (float)v[7], 0.f) * w1.w;
#pragma unroll
    for (int m = 16; m >= 1; m >>= 1) s += __shfl_xor(s, m, 64);
    if (l32 == 0) out[e] = s + bd2[0];
}

// ---------------------------------------------------------------------------
extern "C" void kernel_launch(void* const* d_in, const int* in_sizes, int n_in,
                              void* d_out, int out_size, void* d_ws, size_t ws_size,
                              hipStream_t stream)
{
    const float* x_sotu  = (const float*)d_in[0];
    const float* x_taxon = (const float*)d_in[1];
    const int* edge_src  = (const int*)d_in[2];
    const int* edge_dst  = (const int*)d_in[3];
    const int* label_src = (const int*)d_in[4];
    const int* label_dst = (const int*)d_in[5];
    const float* Wl1_st = (const float*)d_in[6];
    const float* bl1_st = (const float*)d_in[7];
    const float* Wr1_st = (const float*)d_in[8];
    const float* Wl1_ts = (const float*)d_in[9];
    const float* bl1_ts = (const float*)d_in[10];
    const float* Wr1_ts = (const float*)d_in[11];
    const float* Wl2_st = (const float*)d_in[12];
    const float* bl2_st = (const float*)d_in[13];
    const float* Wr2_st = (const float*)d_in[14];
    const float* Wl2_ts = (const float*)d_in[15];
    const float* bl2_ts = (const float*)d_in[16];
    const float* Wr2_ts = (const float*)d_in[17];
    const float* Wlin_s = (const float*)d_in[18];
    const float* blin_s = (const float*)d_in[19];
    const float* Wlin_t = (const float*)d_in[20];
    const float* blin_t = (const float*)d_in[21];
    const float* Wd1 = (const float*)d_in[22];
    const float* bd1 = (const float*)d_in[23];
    const float* Wd2 = (const float*)d_in[24];
    const float* bd2 = (const float*)d_in[25];

    // -------- workspace layout --------
    int* wi = (int*)d_ws;
    size_t io = 0;
    int* cnt_s   = wi + io; io += NS;
    int* cnt_t   = wi + io; io += NT;
    int* rowptr_s = wi + io; io += NS + 8;
    int* rowptr_t = wi + io; io += NT + 8;
    int* col_s   = wi + io; io += E_EDGES;
    int* col_t   = wi + io; io += E_EDGES;
    unsigned* stg_s = (unsigned*)(wi + io); io += E_EDGES;
    unsigned* stg_t = (unsigned*)(wi + io); io += E_EDGES;
    int* bsum_s  = wi + io; io += 128;
    int* bsum_t  = wi + io; io += 128;
    int* gcur_t  = wi + io; io += 128;
    int* gcur_s  = wi + io; io += 128;
    io = (io + 63) & ~(size_t)63;

    ushort_t* wb = (ushort_t*)(wi + io);
    size_t bo = 0;
    ushort_t* m_s  = wb + bo; bo += (size_t)NS * H;   // U (fp16) overlays m_s
    ushort_t* h1_s = wb + bo; bo += (size_t)NS * H;
    ushort_t* m_t  = wb + bo; bo += (size_t)NT * H;   // V (fp16) overlays m_t
    ushort_t* h1_t = wb + bo; bo += (size_t)NT * H;
    ushort_t* h2_s = wb + bo; bo += (size_t)NS * H;
    ushort_t* h2_t = wb + bo; bo += (size_t)NT * H;
    ushort_t* xs_b = wb + bo; bo += (size_t)NS * DS;
    ushort_t* xt_b = wb + bo; bo += (size_t)NT * DT;
    ushort_t* Pt   = wb + bo; bo += (size_t)NT * H;
    ushort_t* wb_l1st = wb + bo; bo += H * DS;
    ushort_t* wb_r1st = wb + bo; bo += H * DT;
    ushort_t* wb_l1ts = wb + bo; bo += H * DT;
    ushort_t* wb_r1ts = wb + bo; bo += H * DS;
    ushort_t* wb_l2st = wb + bo; bo += H * H;
    ushort_t* wb_r2st = wb + bo; bo += H * H;
    ushort_t* wb_l2ts = wb + bo; bo += H * H;
    ushort_t* wb_r2ts = wb + bo; bo += H * H;
    ushort_t* wcb_s   = wb + bo; bo += H * H;
    ushort_t* wcb_t   = wb + bo; bo += H * H;
    bo = (bo + 7) & ~(size_t)7;

    float* wf = (float*)(wb + bo);
    size_t fo = 0;
    float* Wc_s = wf + fo; fo += H * H;
    float* Wc_t = wf + fo; fo += H * H;
    float* bu   = wf + fo; fo += 256;
    float* bv   = wf + fo; fo += 256;

    _Float16* U = (_Float16*)m_s;
    _Float16* V = (_Float16*)m_t;

    const dim3 blk(256);
    auto mg = [](int M) { return dim3(((M + 127) / 128) * 2); };
    const int nbS = (NS + 1023) / 1024;   // 98
    const int nbT = (NT + 1023) / 1024;   // 20
    const int nA = (E_EDGES + CHUNK - 1) / CHUNK;

    // ---- decoder weight folding ----
    fold_kernel<<<513, blk, 0, stream>>>(Wd1, bd1, Wlin_s, blin_s, Wlin_t, blin_t,
                                         Wc_s, Wc_t, bu, bv);

    // ---- batched fp32->bf16 conversion ----
    {
        CvtJobs jb; int c = 0, total4 = 0;
        auto addj = [&](const float* s, ushort_t* d, int n) {
            jb.src[c] = s; jb.dst[c] = d; jb.n4[c] = n / 4; total4 += n / 4; c++;
        };
        addj(x_sotu, xs_b, NS * DS);
        addj(x_taxon, xt_b, NT * DT);
        addj(Wl1_st, wb_l1st, H * DS);
        addj(Wr1_st, wb_r1st, H * DT);
        addj(Wl1_ts, wb_l1ts, H * DT);
        addj(Wr1_ts, wb_r1ts, H * DS);
        addj(Wl2_st, wb_l2st, H * H);
        addj(Wr2_st, wb_r2st, H * H);
        addj(Wl2_ts, wb_l2ts, H * H);
        addj(Wr2_ts, wb_r2ts, H * H);
        addj(Wc_s, wcb_s, H * H);
        addj(Wc_t, wcb_t, H * H);
        jb.cnt = c;
        cvt_kernel<<<(total4 + 255) / 256, blk, 0, stream>>>(jb, total4);
    }

    // ---- CSR build: count -> scan -> binned two-pass fill ----
    hipMemsetAsync(cnt_s, 0, (size_t)(NS + NT) * sizeof(int), stream);
    count_kernel<<<(E_EDGES + 255) / 256, blk, 0, stream>>>(edge_src, edge_dst,
                                                            cnt_s, cnt_t, E_EDGES);
    psum_kernel<<<nbS + nbT, blk, 0, stream>>>(cnt_s, cnt_t, bsum_s, bsum_t, nbS);
    sbsum_kernel<<<2, 64, 0, stream>>>(bsum_s, bsum_t, nbS, nbT);
    sblock_kernel<<<nbS + nbT, blk, 0, stream>>>(cnt_s, cnt_t, bsum_s, bsum_t,
                                                 rowptr_s, rowptr_t, nbS);
    binit_kernel<<<1, blk, 0, stream>>>(rowptr_t, rowptr_s, gcur_t, gcur_s);
    binA_kernel<<<nA, blk, 0, stream>>>(edge_dst, edge_src, E_EDGES,
                                        NB_T, SH_T, VB_T, gcur_t, stg_t);
    binA_kernel<<<nA, blk, 0, stream>>>(edge_src, edge_dst, E_EDGES,
                                        NB_S, SH_S, VB_S, gcur_s, stg_s);
    binB_kernel<<<NB_T, blk, 0, stream>>>(stg_t, rowptr_t, NT, 1 << SH_T, VB_T, col_t);
    binB_kernel<<<NB_S, blk, 0, stream>>>(stg_s, rowptr_s, NS, 1 << SH_S, VB_S, col_s);

    // ---- layer 1 ----
    mgemm_kernel<<<mg(NT), blk, 0, stream>>>(xt_b, wb_l1ts, DT, nullptr, nullptr, 0,
                                             nullptr, nullptr, Pt, NT, 0);
    gather_mean_kernel<<<(NT + 7) / 8, blk, 0, stream>>>(
        xs_b, rowptr_t, cnt_t, col_t, m_t, NT);
    gather_mean_kernel<<<(NS + 7) / 8, blk, 0, stream>>>(
        Pt, rowptr_s, cnt_s, col_s, m_s, NS);
    mgemm_kernel<<<mg(NT), blk, 0, stream>>>(m_t, wb_l1st, H, xt_b, wb_r1st, DT,
                                             nullptr, bl1_st, h1_t, NT, 1);
    mgemm_kernel<<<mg(NS), blk, 0, stream>>>(xs_b, wb_r1ts, DS, nullptr, nullptr, 0,
                                             m_s, bl1_ts, h1_s, NS, 1);

    // ---- layer 2 ----
    mgemm_kernel<<<mg(NT), blk, 0, stream>>>(h1_t, wb_l2ts, H, nullptr, nullptr, 0,
                                             nullptr, nullptr, Pt, NT, 0);
    gather_mean_kernel<<<(NT + 7) / 8, blk, 0, stream>>>(
        h1_s, rowptr_t, cnt_t, col_t, m_t, NT);
    gather_mean_kernel<<<(NS + 7) / 8, blk, 0, stream>>>(
        Pt, rowptr_s, cnt_s, col_s, m_s, NS);
    mgemm_kernel<<<mg(NT), blk, 0, stream>>>(m_t, wb_l2st, H, h1_t, wb_r2st, H,
                                             nullptr, bl2_st, h2_t, NT, 1);
    mgemm_kernel<<<mg(NS), blk, 0, stream>>>(h1_s, wb_r2ts, H, nullptr, nullptr, 0,
                                             m_s, bl2_ts, h2_s, NS, 1);

    // ---- decoder: U/V node potentials (fp16 out) + per-edge reduce ----
    mgemm_kernel<<<mg(NS), blk, 0, stream>>>(h2_s, wcb_s, H, nullptr, nullptr, 0,
                                             nullptr, bu, U, NS, 2);
    mgemm_kernel<<<mg(NT), blk, 0, stream>>>(h2_t, wcb_t, H, nullptr, nullptr, 0,
                                             nullptr, bv, V, NT, 2);
    edge_score_kernel<<<(EL_EDGES + 7) / 8, blk, 0, stream>>>(
        U, V, label_src, label_dst, Wd2, bd2, (float*)d_out, EL_EDGES);
}

// Round 12
// 903.096 us; speedup vs baseline: 1.3190x; 1.0779x over previous
//
#include <hip/hip_runtime.h>

// ---------------------------------------------------------------------------
// Hetero GraphSAGE (2 layers) + edge decoder.
// R1: CSR-gather aggregation. R4: algebraic restructure (U/V decoder split,
//     weight folding, project-before-aggregate). FLOP 1.23e11 -> 5.3e10.
// R5: bf16 MFMA GEMMs + bf16 activations. R6: fp16 U/V, fused CSR aux.
// R8: two-pass LDS-binned CSR fill. R10: XCD-paired swizzle (FETCH 76->51MB,
//     proved mgemm latency-bound). R11: reg prefetch ~neutral (compiler had
//     already hoisted; stall = occupancy).
// R12: mgemm -> 512 threads / 8 waves, wave tile 32x64 (acc[2][4] = 32 AGPR
//     vs 64). Regs/wave ~136 -> ~96: 3 -> 5 waves/SIMD ceiling, occupancy
//     24% -> ~50%. Same 128x128 block tile / LDS / swizzle / prefetch.
// ---------------------------------------------------------------------------

constexpr int NS = 100000, NT = 20000;
constexpr int E_EDGES = 800000, EL_EDGES = 200000;
constexpr int DS = 256, DT = 128, H = 256;

constexpr int NB_T = 79, SH_T = 8, VB_T = 17;
constexpr int NB_S = 98, SH_S = 10, VB_S = 15;
constexpr int BIN_CAP = 96, CHUNK = 2048;

typedef __attribute__((ext_vector_type(8))) short short8;
typedef __attribute__((ext_vector_type(4))) float float4v;
typedef __attribute__((ext_vector_type(8))) _Float16 half8v;
typedef unsigned short ushort_t;

__device__ __forceinline__ float bf2f(unsigned int u) {
    union { unsigned int i; float f; } x; x.i = u << 16; return x.f;
}
__device__ __forceinline__ unsigned short f2bf(float f) {
    union { float f; unsigned int i; } x; x.f = f;
    unsigned int r = x.i + 0x7FFFu + ((x.i >> 16) & 1u);   // RNE
    return (unsigned short)(r >> 16);
}

// --------------------------- MFMA GEMM -------------------------------------
// C[M,256] = op( A1@W1^T [+ A2@W2^T] [+ Add] [+ bias] )
// 128x128 block tile, BK=32, LDS stride 40, XCD-paired swizzle, reg prefetch.
// R12: 512 threads / 8 waves; wave (g=wave>>1, h=wave&1) owns rows
// [32g,32g+32) x cols [64h,64h+64): acc[2][4], 32 AGPR/wave.
// flags: 1 = relu, 2 = fp16 output (else bf16)
__global__ __launch_bounds__(512) void mgemm_kernel(
    const ushort_t* __restrict__ A1, const ushort_t* __restrict__ W1, int K1,
    const ushort_t* __restrict__ A2, const ushort_t* __restrict__ W2, int K2,
    const ushort_t* __restrict__ Add, const float* __restrict__ bias,
    void* __restrict__ Cout, int M, int flags)
{
    __shared__ ushort_t As[128][40];
    __shared__ ushort_t Bs[128][40];
    const int tid = threadIdx.x;

    // ---- XCD-paired swizzle: bid -> (rowblk, colblk) ----
    const int nx = (M + 127) >> 7;          // row-blocks
    const int nx8 = nx & ~7;                // swizzled region (multiple of 8)
    const int bid = blockIdx.x;
    int rowblk, colblk;
    if (bid < nx8 * 2) {
        const int group = bid >> 4;         // 16 blocks per group
        const int xcd = bid & 7;
        const int half = (bid >> 3) & 1;
        rowblk = group * 8 + xcd;
        colblk = half;
    } else {
        const int r = bid - nx8 * 2;
        rowblk = nx8 + (r >> 1);
        colblk = r & 1;
    }
    const int row0 = rowblk * 128, col0 = colblk * 128;

    const int wave = tid >> 6, lane = tid & 63;
    const int wrow = (wave >> 1) * 32;      // 4 row-groups of 32
    const int wcol = (wave & 1) * 64;       // 2 col-groups of 64
    const int m16 = lane & 15, quad = lane >> 4;
    const int sr = tid >> 2;                // staging row 0..127
    const int skc = (tid & 3) * 8;          // k-chunk (ushorts): 0,8,16,24

    float4v acc[2][4];
#pragma unroll
    for (int i = 0; i < 2; i++)
#pragma unroll
        for (int j = 0; j < 4; j++) acc[i][j] = (float4v){0.f, 0.f, 0.f, 0.f};

#pragma unroll 1
    for (int pass = 0; pass < 2; pass++) {
        const ushort_t* A = pass ? A2 : A1;
        const ushort_t* W = pass ? W2 : W1;
        const int K = pass ? K2 : K1;
        if (!A) break;
        const int gra = row0 + sr;
        const bool oka = gra < M;
        const ushort_t* Ap = A + (size_t)gra * K + skc;
        const ushort_t* Wp = W + (size_t)(col0 + sr) * K + skc;

        // preload tile 0
        uint4 a0 = make_uint4(0, 0, 0, 0);
        if (oka) a0 = *(const uint4*)Ap;
        uint4 b0 = *(const uint4*)Wp;

        for (int k0 = 0; k0 < K; k0 += 32) {
            __syncthreads();                 // prev iter done reading LDS
            *(uint4*)&As[sr][skc] = a0;
            *(uint4*)&Bs[sr][skc] = b0;
            __syncthreads();                 // LDS ready
            if (k0 + 32 < K) {               // prefetch tile k+1
                a0 = make_uint4(0, 0, 0, 0);
                if (oka) a0 = *(const uint4*)(Ap + k0 + 32);
                b0 = *(const uint4*)(Wp + k0 + 32);
            }
            short8 af[2], bf[4];
#pragma unroll
            for (int i = 0; i < 2; i++)
                af[i] = *(const short8*)&As[wrow + i * 16 + m16][quad * 8];
#pragma unroll
            for (int j = 0; j < 4; j++)
                bf[j] = *(const short8*)&Bs[wcol + j * 16 + m16][quad * 8];
#pragma unroll
            for (int i = 0; i < 2; i++)
#pragma unroll
                for (int j = 0; j < 4; j++)
                    acc[i][j] = __builtin_amdgcn_mfma_f32_16x16x32_bf16(
                        af[i], bf[j], acc[i][j], 0, 0, 0);
        }
    }

    const bool relu = flags & 1, f16out = flags & 2;
#pragma unroll
    for (int i = 0; i < 2; i++) {
        const int rbase = row0 + wrow + i * 16 + quad * 4;
#pragma unroll
        for (int r = 0; r < 4; r++) {
            const int row = rbase + r;
            if (row >= M) continue;
#pragma unroll
            for (int j = 0; j < 4; j++) {
                const int col = col0 + wcol + j * 16 + m16;
                float v = acc[i][j][r];
                if (Add) v += bf2f((unsigned int)Add[(size_t)row * 256 + col]);
                if (bias) v += bias[col];
                if (relu) v = fmaxf(v, 0.f);
                if (f16out) ((_Float16*)Cout)[(size_t)row * 256 + col] = (_Float16)v;
                else ((ushort_t*)Cout)[(size_t)row * 256 + col] = f2bf(v);
            }
        }
    }
}

// --------------------- batched fp32 -> bf16 convert ------------------------
struct CvtJobs {
    const float* src[14];
    ushort_t* dst[14];
    int n4[14];
    int cnt;
};

__global__ __launch_bounds__(256) void cvt_kernel(CvtJobs jb, int total4)
{
    int t = blockIdx.x * blockDim.x + threadIdx.x;
    if (t >= total4) return;
    int idx = t;
    for (int k = 0; k < jb.cnt; k++) {
        if (idx < jb.n4[k]) {
            float4 v = ((const float4*)jb.src[k])[idx];
            uint2 o;
            o.x = (unsigned int)f2bf(v.x) | ((unsigned int)f2bf(v.y) << 16);
            o.y = (unsigned int)f2bf(v.z) | ((unsigned int)f2bf(v.w) << 16);
            *(uint2*)(jb.dst[k] + (size_t)idx * 4) = o;
            return;
        }
        idx -= jb.n4[k];
    }
}

// -------------- decoder weight folding (one fused kernel) ------------------
__global__ __launch_bounds__(256) void fold_kernel(
    const float* __restrict__ Wd1, const float* __restrict__ bd1,
    const float* __restrict__ Wlin_s, const float* __restrict__ blin_s,
    const float* __restrict__ Wlin_t, const float* __restrict__ blin_t,
    float* __restrict__ Wc_s, float* __restrict__ Wc_t,
    float* __restrict__ bu, float* __restrict__ bv)
{
    const int b = blockIdx.x, t = threadIdx.x;
    if (b < 256) {
        float s = 0.f;
        for (int k = 0; k < 256; k++) s += Wd1[b * 512 + k] * Wlin_s[k * 256 + t];
        Wc_s[b * 256 + t] = s;
    } else if (b < 512) {
        const int h = b - 256;
        float s = 0.f;
        for (int k = 0; k < 256; k++) s += Wd1[h * 512 + 256 + k] * Wlin_t[k * 256 + t];
        Wc_t[h * 256 + t] = s;
    } else {
        float su = 0.f, sv = 0.f;
        for (int k = 0; k < 256; k++) {
            su += Wd1[t * 512 + k] * blin_s[k];
            sv += Wd1[t * 512 + 256 + k] * blin_t[k];
        }
        bu[t] = bd1[t] + su;
        bv[t] = sv;
    }
}

// --------------------------- CSR build -------------------------------------
__global__ void count_kernel(const int* __restrict__ src, const int* __restrict__ dst,
                             int* __restrict__ cnt_s, int* __restrict__ cnt_t, int E)
{
    int e = blockIdx.x * blockDim.x + threadIdx.x;
    if (e < E) {
        atomicAdd(&cnt_s[src[e]], 1);
        atomicAdd(&cnt_t[dst[e]], 1);
    }
}

__global__ __launch_bounds__(256) void psum_kernel(
    const int* __restrict__ cnt_s, const int* __restrict__ cnt_t,
    int* __restrict__ bsum_s, int* __restrict__ bsum_t, int nbS)
{
    const bool isS = (int)blockIdx.x < nbS;
    const int blk = isS ? blockIdx.x : blockIdx.x - nbS;
    const int N = isS ? NS : NT;
    const int* cnt = isS ? cnt_s : cnt_t;
    int* bsum = isS ? bsum_s : bsum_t;
    __shared__ int sdata[256];
    const int t = threadIdx.x;
    const int base = blk * 1024;
    int s = 0;
    for (int i = t; i < 1024; i += 256) {
        int idx = base + i;
        s += (idx < N) ? cnt[idx] : 0;
    }
    sdata[t] = s; __syncthreads();
    for (int off = 128; off > 0; off >>= 1) {
        if (t < off) sdata[t] += sdata[t + off];
        __syncthreads();
    }
    if (t == 0) bsum[blk] = sdata[0];
}

__global__ void sbsum_kernel(int* __restrict__ bsum_s, int* __restrict__ bsum_t,
                             int nbS, int nbT)
{
    if (threadIdx.x != 0) return;
    int* b = blockIdx.x ? bsum_t : bsum_s;
    int nb = blockIdx.x ? nbT : nbS;
    int run = 0;
    for (int i = 0; i < nb; i++) { int v = b[i]; b[i] = run; run += v; }
}

__global__ __launch_bounds__(256) void sblock_kernel(
    const int* __restrict__ cnt_s, const int* __restrict__ cnt_t,
    const int* __restrict__ bsum_s, const int* __restrict__ bsum_t,
    int* __restrict__ rowptr_s, int* __restrict__ rowptr_t, int nbS)
{
    const bool isS = (int)blockIdx.x < nbS;
    const int blk = isS ? blockIdx.x : blockIdx.x - nbS;
    const int N = isS ? NS : NT;
    const int* cnt = isS ? cnt_s : cnt_t;
    const int* bsum = isS ? bsum_s : bsum_t;
    int* rowptr = isS ? rowptr_s : rowptr_t;
    __shared__ int sc[256];
    const int t = threadIdx.x;
    const int base = blk * 1024 + t * 4;
    int v[4]; int s = 0;
#pragma unroll
    for (int j = 0; j < 4; j++) {
        int idx = base + j;
        v[j] = (idx < N) ? cnt[idx] : 0;
        s += v[j];
    }
    sc[t] = s; __syncthreads();
    for (int off = 1; off < 256; off <<= 1) {
        int add = (t >= off) ? sc[t - off] : 0;
        __syncthreads();
        sc[t] += add;
        __syncthreads();
    }
    int excl = sc[t] - s + bsum[blk];
#pragma unroll
    for (int j = 0; j < 4; j++) {
        int idx = base + j;
        if (idx < N) rowptr[idx] = excl;
        if (idx == N - 1) rowptr[N] = excl + v[j];
        excl += v[j];
    }
}

__global__ void binit_kernel(const int* __restrict__ rowptr_t,
                             const int* __restrict__ rowptr_s,
                             int* __restrict__ gcur_t, int* __restrict__ gcur_s)
{
    int t = threadIdx.x;
    if (t < NB_T) gcur_t[t] = rowptr_t[t << SH_T];
    if (t < NB_S) gcur_s[t] = rowptr_s[t << SH_S];
}

__global__ __launch_bounds__(256) void binA_kernel(
    const int* __restrict__ key, const int* __restrict__ val, int E,
    int nbins, int shift, int vbits,
    int* __restrict__ gcur, unsigned* __restrict__ stg)
{
    __shared__ unsigned bins[NB_S * BIN_CAP];
    __shared__ int lcnt[NB_S], gbase[NB_S];
    const int tid = threadIdx.x;
    const int base = blockIdx.x * CHUNK;
    for (int i = tid; i < nbins; i += 256) lcnt[i] = 0;
    __syncthreads();
    const unsigned lowmask = (1u << shift) - 1u;
#pragma unroll
    for (int k = 0; k < CHUNK / 256; k++) {
        int e = base + k * 256 + tid;
        if (e < E) {
            int kk = key[e];
            int b = kk >> shift;
            unsigned pk = (((unsigned)kk & lowmask) << vbits) | (unsigned)val[e];
            int c = atomicAdd(&lcnt[b], 1);
            if (c < BIN_CAP) bins[b * BIN_CAP + c] = pk;
            else { int p = atomicAdd(&gcur[b], 1); stg[p] = pk; }
        }
    }
    __syncthreads();
    if (tid < nbins) gbase[tid] = atomicAdd(&gcur[tid], min(lcnt[tid], BIN_CAP));
    __syncthreads();
    for (int b = 0; b < nbins; b++) {
        int c = min(lcnt[b], BIN_CAP);
        for (int i = tid; i < c; i += 256) stg[gbase[b] + i] = bins[b * BIN_CAP + i];
    }
}

__global__ __launch_bounds__(256) void binB_kernel(
    const unsigned* __restrict__ stg, const int* __restrict__ rowptr,
    int N, int node_per, int vbits, int* __restrict__ colout)
{
    __shared__ int cur[1024];
    const int tid = threadIdx.x;
    const int node0 = blockIdx.x * node_per;
    const int nn = min(node_per, N - node0);
    for (int i = tid; i < nn; i += 256) cur[i] = rowptr[node0 + i];
    const int estart = rowptr[node0];
    const int eend = rowptr[node0 + nn];
    __syncthreads();
    const unsigned vmask = (1u << vbits) - 1u;
    for (int i = estart + tid; i < eend; i += 256) {
        unsigned v = stg[i];
        int kl = (int)(v >> vbits);
        int pos = atomicAdd(&cur[kl], 1);
        colout[pos] = (int)(v & vmask);
    }
}

// ------------------- gather mean (bf16 rows, fp32 accum) -------------------
__global__ __launch_bounds__(256) void gather_mean_kernel(
    const ushort_t* __restrict__ X, const int* __restrict__ rowptr,
    const int* __restrict__ cnt, const int* __restrict__ col,
    ushort_t* __restrict__ out, int N)
{
    const int node = blockIdx.x * 8 + (threadIdx.x >> 5);
    const int c = (threadIdx.x & 31) * 8;
    if (node >= N) return;
    const int beg = rowptr[node];
    const int deg = cnt[node];
    const int end = beg + deg;
    float a[8] = {0, 0, 0, 0, 0, 0, 0, 0};
    float b[8] = {0, 0, 0, 0, 0, 0, 0, 0};
    int i = beg;
    for (; i + 1 < end; i += 2) {
        uint4 v = *(const uint4*)&X[(size_t)col[i] * 256 + c];
        uint4 w = *(const uint4*)&X[(size_t)col[i + 1] * 256 + c];
        a[0] += bf2f(v.x & 0xffff); a[1] += bf2f(v.x >> 16);
        a[2] += bf2f(v.y & 0xffff); a[3] += bf2f(v.y >> 16);
        a[4] += bf2f(v.z & 0xffff); a[5] += bf2f(v.z >> 16);
        a[6] += bf2f(v.w & 0xffff); a[7] += bf2f(v.w >> 16);
        b[0] += bf2f(w.x & 0xffff); b[1] += bf2f(w.x >> 16);
        b[2] += bf2f(w.y & 0xffff); b[3] += bf2f(w.y >> 16);
        b[4] += bf2f(w.z & 0xffff); b[5] += bf2f(w.z >> 16);
        b[6] += bf2f(w.w & 0xffff); b[7] += bf2f(w.w >> 16);
    }
    if (i < end) {
        uint4 v = *(const uint4*)&X[(size_t)col[i] * 256 + c];
        a[0] += bf2f(v.x & 0xffff); a[1] += bf2f(v.x >> 16);
        a[2] += bf2f(v.y & 0xffff); a[3] += bf2f(v.y >> 16);
        a[4] += bf2f(v.z & 0xffff); a[5] += bf2f(v.z >> 16);
        a[6] += bf2f(v.w & 0xffff); a[7] += bf2f(v.w >> 16);
    }
    float inv = 1.f / fmaxf((float)deg, 1.f);
    uint4 o;
    o.x = (unsigned int)f2bf((a[0] + b[0]) * inv) | ((unsigned int)f2bf((a[1] + b[1]) * inv) << 16);
    o.y = (unsigned int)f2bf((a[2] + b[2]) * inv) | ((unsigned int)f2bf((a[3] + b[3]) * inv) << 16);
    o.z = (unsigned int)f2bf((a[4] + b[4]) * inv) | ((unsigned int)f2bf((a[5] + b[5]) * inv) << 16);
    o.w = (unsigned int)f2bf((a[6] + b[6]) * inv) | ((unsigned int)f2bf((a[7] + b[7]) * inv) << 16);
    *(uint4*)&out[(size_t)node * 256 + c] = o;
}

// ------------------------- per-edge score (fp16 U/V) -----------------------
__global__ __launch_bounds__(256) void edge_score_kernel(
    const _Float16* __restrict__ U, const _Float16* __restrict__ V,
    const int* __restrict__ ls, const int* __restrict__ ld,
    const float* __restrict__ Wd2, const float* __restrict__ bd2,
    float* __restrict__ out, int EL)
{
    const int l32 = threadIdx.x & 31;
    const int e = blockIdx.x * 8 + (threadIdx.x >> 5);
    if (e >= EL) return;
    const int c = l32 * 8;
    half8v u = *(const half8v*)&U[(size_t)ls[e] * 256 + c];
    half8v v = *(const half8v*)&V[(size_t)ld[e] * 256 + c];
    float4 w0 = *(const float4*)&Wd2[c];
    float4 w1 = *(const float4*)&Wd2[c + 4];
    float s = fmaxf((float)u[0] + (float)v[0], 0.f) * w0.x
            + fmaxf((float)u[1] + (float)v[1], 0.f) * w0.y
            + fmaxf((float)u[2] + (float)v[2], 0.f) * w0.z
            + fmaxf((float)u[3] + (float)v[3], 0.f) * w0.w
            + fmaxf((float)u[4] + (float)v[4], 0.f) * w1.x
            + fmaxf((float)u[5] + (float)v[5], 0.f) * w1.y
            + fmaxf((float)u[6] + (float)v[6], 0.f) * w1.z
            + fmaxf((float)u[7] + (float)v[7], 0.f) * w1.w;
#pragma unroll
    for (int m = 16; m >= 1; m >>= 1) s += __shfl_xor(s, m, 64);
    if (l32 == 0) out[e] = s + bd2[0];
}

// ---------------------------------------------------------------------------
extern "C" void kernel_launch(void* const* d_in, const int* in_sizes, int n_in,
                              void* d_out, int out_size, void* d_ws, size_t ws_size,
                              hipStream_t stream)
{
    const float* x_sotu  = (const float*)d_in[0];
    const float* x_taxon = (const float*)d_in[1];
    const int* edge_src  = (const int*)d_in[2];
    const int* edge_dst  = (const int*)d_in[3];
    const int* label_src = (const int*)d_in[4];
    const int* label_dst = (const int*)d_in[5];
    const float* Wl1_st = (const float*)d_in[6];
    const float* bl1_st = (const float*)d_in[7];
    const float* Wr1_st = (const float*)d_in[8];
    const float* Wl1_ts = (const float*)d_in[9];
    const float* bl1_ts = (const float*)d_in[10];
    const float* Wr1_ts = (const float*)d_in[11];
    const float* Wl2_st = (const float*)d_in[12];
    const float* bl2_st = (const float*)d_in[13];
    const float* Wr2_st = (const float*)d_in[14];
    const float* Wl2_ts = (const float*)d_in[15];
    const float* bl2_ts = (const float*)d_in[16];
    const float* Wr2_ts = (const float*)d_in[17];
    const float* Wlin_s = (const float*)d_in[18];
    const float* blin_s = (const float*)d_in[19];
    const float* Wlin_t = (const float*)d_in[20];
    const float* blin_t = (const float*)d_in[21];
    const float* Wd1 = (const float*)d_in[22];
    const float* bd1 = (const float*)d_in[23];
    const float* Wd2 = (const float*)d_in[24];
    const float* bd2 = (const float*)d_in[25];

    // -------- workspace layout --------
    int* wi = (int*)d_ws;
    size_t io = 0;
    int* cnt_s   = wi + io; io += NS;
    int* cnt_t   = wi + io; io += NT;
    int* rowptr_s = wi + io; io += NS + 8;
    int* rowptr_t = wi + io; io += NT + 8;
    int* col_s   = wi + io; io += E_EDGES;
    int* col_t   = wi + io; io += E_EDGES;
    unsigned* stg_s = (unsigned*)(wi + io); io += E_EDGES;
    unsigned* stg_t = (unsigned*)(wi + io); io += E_EDGES;
    int* bsum_s  = wi + io; io += 128;
    int* bsum_t  = wi + io; io += 128;
    int* gcur_t  = wi + io; io += 128;
    int* gcur_s  = wi + io; io += 128;
    io = (io + 63) & ~(size_t)63;

    ushort_t* wb = (ushort_t*)(wi + io);
    size_t bo = 0;
    ushort_t* m_s  = wb + bo; bo += (size_t)NS * H;   // U (fp16) overlays m_s
    ushort_t* h1_s = wb + bo; bo += (size_t)NS * H;
    ushort_t* m_t  = wb + bo; bo += (size_t)NT * H;   // V (fp16) overlays m_t
    ushort_t* h1_t = wb + bo; bo += (size_t)NT * H;
    ushort_t* h2_s = wb + bo; bo += (size_t)NS * H;
    ushort_t* h2_t = wb + bo; bo += (size_t)NT * H;
    ushort_t* xs_b = wb + bo; bo += (size_t)NS * DS;
    ushort_t* xt_b = wb + bo; bo += (size_t)NT * DT;
    ushort_t* Pt   = wb + bo; bo += (size_t)NT * H;
    ushort_t* wb_l1st = wb + bo; bo += H * DS;
    ushort_t* wb_r1st = wb + bo; bo += H * DT;
    ushort_t* wb_l1ts = wb + bo; bo += H * DT;
    ushort_t* wb_r1ts = wb + bo; bo += H * DS;
    ushort_t* wb_l2st = wb + bo; bo += H * H;
    ushort_t* wb_r2st = wb + bo; bo += H * H;
    ushort_t* wb_l2ts = wb + bo; bo += H * H;
    ushort_t* wb_r2ts = wb + bo; bo += H * H;
    ushort_t* wcb_s   = wb + bo; bo += H * H;
    ushort_t* wcb_t   = wb + bo; bo += H * H;
    bo = (bo + 7) & ~(size_t)7;

    float* wf = (float*)(wb + bo);
    size_t fo = 0;
    float* Wc_s = wf + fo; fo += H * H;
    float* Wc_t = wf + fo; fo += H * H;
    float* bu   = wf + fo; fo += 256;
    float* bv   = wf + fo; fo += 256;

    _Float16* U = (_Float16*)m_s;
    _Float16* V = (_Float16*)m_t;

    const dim3 blk(256);
    const dim3 blk512(512);
    auto mg = [](int M) { return dim3(((M + 127) / 128) * 2); };
    const int nbS = (NS + 1023) / 1024;   // 98
    const int nbT = (NT + 1023) / 1024;   // 20
    const int nA = (E_EDGES + CHUNK - 1) / CHUNK;

    // ---- decoder weight folding ----
    fold_kernel<<<513, blk, 0, stream>>>(Wd1, bd1, Wlin_s, blin_s, Wlin_t, blin_t,
                                         Wc_s, Wc_t, bu, bv);

    // ---- batched fp32->bf16 conversion ----
    {
        CvtJobs jb; int c = 0, total4 = 0;
        auto addj = [&](const float* s, ushort_t* d, int n) {
            jb.src[c] = s; jb.dst[c] = d; jb.n4[c] = n / 4; total4 += n / 4; c++;
        };
        addj(x_sotu, xs_b, NS * DS);
        addj(x_taxon, xt_b, NT * DT);
        addj(Wl1_st, wb_l1st, H * DS);
        addj(Wr1_st, wb_r1st, H * DT);
        addj(Wl1_ts, wb_l1ts, H * DT);
        addj(Wr1_ts, wb_r1ts, H * DS);
        addj(Wl2_st, wb_l2st, H * H);
        addj(Wr2_st, wb_r2st, H * H);
        addj(Wl2_ts, wb_l2ts, H * H);
        addj(Wr2_ts, wb_r2ts, H * H);
        addj(Wc_s, wcb_s, H * H);
        addj(Wc_t, wcb_t, H * H);
        jb.cnt = c;
        cvt_kernel<<<(total4 + 255) / 256, blk, 0, stream>>>(jb, total4);
    }

    // ---- CSR build: count -> scan -> binned two-pass fill ----
    hipMemsetAsync(cnt_s, 0, (size_t)(NS + NT) * sizeof(int), stream);
    count_kernel<<<(E_EDGES + 255) / 256, blk, 0, stream>>>(edge_src, edge_dst,
                                                            cnt_s, cnt_t, E_EDGES);
    psum_kernel<<<nbS + nbT, blk, 0, stream>>>(cnt_s, cnt_t, bsum_s, bsum_t, nbS);
    sbsum_kernel<<<2, 64, 0, stream>>>(bsum_s, bsum_t, nbS, nbT);
    sblock_kernel<<<nbS + nbT, blk, 0, stream>>>(cnt_s, cnt_t, bsum_s, bsum_t,
                                                 rowptr_s, rowptr_t, nbS);
    binit_kernel<<<1, blk, 0, stream>>>(rowptr_t, rowptr_s, gcur_t, gcur_s);
    binA_kernel<<<nA, blk, 0, stream>>>(edge_dst, edge_src, E_EDGES,
                                        NB_T, SH_T, VB_T, gcur_t, stg_t);
    binA_kernel<<<nA, blk, 0, stream>>>(edge_src, edge_dst, E_EDGES,
                                        NB_S, SH_S, VB_S, gcur_s, stg_s);
    binB_kernel<<<NB_T, blk, 0, stream>>>(stg_t, rowptr_t, NT, 1 << SH_T, VB_T, col_t);
    binB_kernel<<<NB_S, blk, 0, stream>>>(stg_s, rowptr_s, NS, 1 << SH_S, VB_S, col_s);

    // ---- layer 1 ----
    mgemm_kernel<<<mg(NT), blk512, 0, stream>>>(xt_b, wb_l1ts, DT, nullptr, nullptr, 0,
                                                nullptr, nullptr, Pt, NT, 0);
    gather_mean_kernel<<<(NT + 7) / 8, blk, 0, stream>>>(
        xs_b, rowptr_t, cnt_t, col_t, m_t, NT);
    gather_mean_kernel<<<(NS + 7) / 8, blk, 0, stream>>>(
        Pt, rowptr_s, cnt_s, col_s, m_s, NS);
    mgemm_kernel<<<mg(NT), blk512, 0, stream>>>(m_t, wb_l1st, H, xt_b, wb_r1st, DT,
                                                nullptr, bl1_st, h1_t, NT, 1);
    mgemm_kernel<<<mg(NS), blk512, 0, stream>>>(xs_b, wb_r1ts, DS, nullptr, nullptr, 0,
                                                m_s, bl1_ts, h1_s, NS, 1);

    // ---- layer 2 ----
    mgemm_kernel<<<mg(NT), blk512, 0, stream>>>(h1_t, wb_l2ts, H, nullptr, nullptr, 0,
                                                nullptr, nullptr, Pt, NT, 0);
    gather_mean_kernel<<<(NT + 7) / 8, blk, 0, stream>>>(
        h1_s, rowptr_t, cnt_t, col_t, m_t, NT);
    gather_mean_kernel<<<(NS + 7) / 8, blk, 0, stream>>>(
        Pt, rowptr_s, cnt_s, col_s, m_s, NS);
    mgemm_kernel<<<mg(NT), blk512, 0, stream>>>(m_t, wb_l2st, H, h1_t, wb_r2st, H,
                                                nullptr, bl2_st, h2_t, NT, 1);
    mgemm_kernel<<<mg(NS), blk512, 0, stream>>>(h1_s, wb_r2ts, H, nullptr, nullptr, 0,
                                                m_s, bl2_ts, h2_s, NS, 1);

    // ---- decoder: U/V node potentials (fp16 out) + per-edge reduce ----
    mgemm_kernel<<<mg(NS), blk512, 0, stream>>>(h2_s, wcb_s, H, nullptr, nullptr, 0,
                                                nullptr, bu, U, NS, 2);
    mgemm_kernel<<<mg(NT), blk512, 0, stream>>>(h2_t, wcb_t, H, nullptr, nullptr, 0,
                                                nullptr, bv, V, NT, 2);
    edge_score_kernel<<<(EL_EDGES + 7) / 8, blk, 0, stream>>>(
        U, V, label_src, label_dst, Wd2, bd2, (float*)d_out, EL_EDGES);
}